// Round 12
// baseline (722.294 us; speedup 1.0000x reference)
//
#include <hip/hip_runtime.h>

#define NU 50000
#define NI 70000
#define NT 120000
#define DD 128
#define EDG 800000
#define CSC ((NT + 255) / 256)      // 469 rows per scan thread
#define CHK 256                     // tn row chunk
#define NBU_TN ((NU + CHK - 1) / CHK)   // 196
#define NBI_TN ((NI + CHK - 1) / CHK)   // 274
#define NB_TN4 (4 * (NBU_TN + NBI_TN))  // 1880 (64x64 quadrant blocks)
#define NBU_M ((NU + 63) / 64)      // 782
#define NBI_M ((NI + 63) / 64)      // 1094
#define NBM (NBU_M + NBI_M)         // 1876
#define NSC ((EDG + 255) / 256)     // 3125 scatter/hist blocks
#define NSPMM (NT / 4)              // 30000 spmm blocks
#define SLOPE 0.5f

typedef __attribute__((ext_vector_type(8))) short bf16x8;
typedef __attribute__((ext_vector_type(4))) float f32x4;
typedef unsigned short u16;
typedef unsigned int u32;

__device__ __forceinline__ float lrelu(float x) { return x >= 0.f ? x : SLOPE * x; }

__device__ __forceinline__ u16 f2bf(float x) {
  union { float f; u32 u; } t; t.f = x;
  u32 r = (t.u + 0x7fffu + ((t.u >> 16) & 1u)) >> 16;
  return (u16)r;
}
__device__ __forceinline__ float bflo(u32 u) {
  union { u32 u; float f; } t; t.u = u << 16; return t.f;
}
__device__ __forceinline__ float bfhi(u32 u) {
  union { u32 u; float f; } t; t.u = u & 0xffff0000u; return t.f;
}
__device__ __forceinline__ float bf1(u16 u) {
  union { u32 u; float f; } t; t.u = (u32)u << 16; return t.f;
}

// ---------------- shared device bodies ----------------

// tn 64x64 quadrant: lat[hh..][dh..] += sum_r A[r][h]*B[r][d] (MFMA).
__device__ __forceinline__ void tn_body(int b, int tid,
                                        const u16* __restrict__ Ab,
                                        const u16* __restrict__ pb,
                                        float* __restrict__ latU,
                                        float* __restrict__ latI,
                                        u32* ATs, u32* BTs) {
  int quad = b & 3, cb = b >> 2;
  bool usr = cb < NBU_TN;
  int n = usr ? NU : NI;
  int gbase = usr ? 0 : NU;
  float* outp = usr ? latU : latI;
  int r0c = (usr ? cb : cb - NBU_TN) * CHK;
  int r1c = min(r0c + CHK, n);
  int hh = (quad >> 1) * 64, dh = (quad & 1) * 64;

  int rp2 = tid & 15;
  int sg = tid >> 4;
  int wv = tid >> 6, lane = tid & 63;
  int t = lane & 15, g = lane >> 4;
  int wr = wv >> 1, wc = wv & 1;

  f32x4 acc[2][2];
#pragma unroll
  for (int a = 0; a < 2; ++a)
#pragma unroll
    for (int c2 = 0; c2 < 2; ++c2) acc[a][c2] = (f32x4){0.f, 0.f, 0.f, 0.f};

  for (int r0 = r0c; r0 < r1c; r0 += 32) {
    int ra = r0 + 2 * rp2, rb2 = ra + 1;
    uint2 a0 = {0,0}, a1 = {0,0}, b0 = {0,0}, b1 = {0,0};
    if (ra < r1c) {
      a0 = *(const uint2*)(Ab + (size_t)(gbase + ra) * DD + hh + sg * 4);
      b0 = *(const uint2*)(pb + (size_t)(gbase + ra) * DD + dh + sg * 4);
    }
    if (rb2 < r1c) {
      a1 = *(const uint2*)(Ab + (size_t)(gbase + rb2) * DD + hh + sg * 4);
      b1 = *(const uint2*)(pb + (size_t)(gbase + rb2) * DD + dh + sg * 4);
    }
    __syncthreads();
#pragma unroll
    for (int j = 0; j < 4; ++j) {
      u32 alo = ((const u32*)&a0)[j >> 1], ahi = ((const u32*)&a1)[j >> 1];
      u32 blo = ((const u32*)&b0)[j >> 1], bhi = ((const u32*)&b1)[j >> 1];
      u32 wa, wb;
      if (j & 1) {
        wa = (alo >> 16) | (ahi & 0xffff0000u);
        wb = (blo >> 16) | (bhi & 0xffff0000u);
      } else {
        wa = (alo & 0xffffu) | (ahi << 16);
        wb = (blo & 0xffffu) | (bhi << 16);
      }
      int c = sg * 4 + j;
      int idx = c * 16 + (rp2 ^ ((c & 3) << 2));
      ATs[idx] = wa;
      BTs[idx] = wb;
    }
    __syncthreads();

    bf16x8 afr[2], bfr[2];
#pragma unroll
    for (int a = 0; a < 2; ++a) {
      int c = wr * 32 + a * 16 + t;
      afr[a] = *(const bf16x8*)&ATs[c * 16 + ((g ^ (c & 3)) << 2)];
    }
#pragma unroll
    for (int c2 = 0; c2 < 2; ++c2) {
      int c = wc * 32 + c2 * 16 + t;
      bfr[c2] = *(const bf16x8*)&BTs[c * 16 + ((g ^ (c & 3)) << 2)];
    }
#pragma unroll
    for (int a = 0; a < 2; ++a)
#pragma unroll
      for (int c2 = 0; c2 < 2; ++c2)
        acc[a][c2] = __builtin_amdgcn_mfma_f32_16x16x32_bf16(
            afr[a], bfr[c2], acc[a][c2], 0, 0, 0);
  }

#pragma unroll
  for (int a = 0; a < 2; ++a) {
    int h = hh + wr * 32 + a * 16 + g * 4;
#pragma unroll
    for (int c2 = 0; c2 < 2; ++c2) {
      int d = dh + wc * 32 + c2 * 16 + t;
#pragma unroll
      for (int j = 0; j < 4; ++j)
        atomicAdd(outp + (h + j) * 128 + d, acc[a][c2][j]);
    }
  }
}

// spmm row: G[r,:] = lrelu(sum val*src[col,:]) + bf16 sidecar.
__device__ __forceinline__ void spmm_body(int r, int tid,
                                          const int* __restrict__ rp,
                                          const int2* __restrict__ se,
                                          const u16* __restrict__ pb,
                                          float* __restrict__ G,
                                          u16* __restrict__ Gb) {
  int lane = tid & 63;
  int p0 = rp[r], p1 = rp[r + 1];
  int q = lane >> 4, l4 = lane & 15;
  float a0 = 0.f, a1 = 0.f, a2 = 0.f, a3 = 0.f;
  float a4 = 0.f, a5 = 0.f, a6 = 0.f, a7 = 0.f;
  int p = p0 + q;
  for (; p + 4 < p1; p += 8) {
    int2 e1 = se[p];
    int2 e2 = se[p + 4];
    uint4 u1 = *(const uint4*)(pb + (size_t)e1.x * DD + l4 * 8);
    uint4 u2 = *(const uint4*)(pb + (size_t)e2.x * DD + l4 * 8);
    float v1 = __int_as_float(e1.y), v2 = __int_as_float(e2.y);
    a0 = fmaf(v1, bflo(u1.x), a0); a1 = fmaf(v1, bfhi(u1.x), a1);
    a2 = fmaf(v1, bflo(u1.y), a2); a3 = fmaf(v1, bfhi(u1.y), a3);
    a4 = fmaf(v1, bflo(u1.z), a4); a5 = fmaf(v1, bfhi(u1.z), a5);
    a6 = fmaf(v1, bflo(u1.w), a6); a7 = fmaf(v1, bfhi(u1.w), a7);
    a0 = fmaf(v2, bflo(u2.x), a0); a1 = fmaf(v2, bfhi(u2.x), a1);
    a2 = fmaf(v2, bflo(u2.y), a2); a3 = fmaf(v2, bfhi(u2.y), a3);
    a4 = fmaf(v2, bflo(u2.z), a4); a5 = fmaf(v2, bfhi(u2.z), a5);
    a6 = fmaf(v2, bflo(u2.w), a6); a7 = fmaf(v2, bfhi(u2.w), a7);
  }
  if (p < p1) {
    int2 e1 = se[p];
    uint4 u1 = *(const uint4*)(pb + (size_t)e1.x * DD + l4 * 8);
    float v1 = __int_as_float(e1.y);
    a0 = fmaf(v1, bflo(u1.x), a0); a1 = fmaf(v1, bfhi(u1.x), a1);
    a2 = fmaf(v1, bflo(u1.y), a2); a3 = fmaf(v1, bfhi(u1.y), a3);
    a4 = fmaf(v1, bflo(u1.z), a4); a5 = fmaf(v1, bfhi(u1.z), a5);
    a6 = fmaf(v1, bflo(u1.w), a6); a7 = fmaf(v1, bfhi(u1.w), a7);
  }
  a0 += __shfl_xor(a0, 16, 64); a0 += __shfl_xor(a0, 32, 64);
  a1 += __shfl_xor(a1, 16, 64); a1 += __shfl_xor(a1, 32, 64);
  a2 += __shfl_xor(a2, 16, 64); a2 += __shfl_xor(a2, 32, 64);
  a3 += __shfl_xor(a3, 16, 64); a3 += __shfl_xor(a3, 32, 64);
  a4 += __shfl_xor(a4, 16, 64); a4 += __shfl_xor(a4, 32, 64);
  a5 += __shfl_xor(a5, 16, 64); a5 += __shfl_xor(a5, 32, 64);
  a6 += __shfl_xor(a6, 16, 64); a6 += __shfl_xor(a6, 32, 64);
  a7 += __shfl_xor(a7, 16, 64); a7 += __shfl_xor(a7, 32, 64);
  if (q == 0) {
    a0 = lrelu(a0); a1 = lrelu(a1); a2 = lrelu(a2); a3 = lrelu(a3);
    a4 = lrelu(a4); a5 = lrelu(a5); a6 = lrelu(a6); a7 = lrelu(a7);
    float4 o1, o2;
    o1.x = a0; o1.y = a1; o1.z = a2; o1.w = a3;
    o2.x = a4; o2.y = a5; o2.z = a6; o2.w = a7;
    *(float4*)(G + (size_t)r * DD + l4 * 8) = o1;
    *(float4*)(G + (size_t)r * DD + l4 * 8 + 4) = o2;
    bf16x8 gb;
    gb[0] = (short)f2bf(a0); gb[1] = (short)f2bf(a1);
    gb[2] = (short)f2bf(a2); gb[3] = (short)f2bf(a3);
    gb[4] = (short)f2bf(a4); gb[5] = (short)f2bf(a5);
    gb[6] = (short)f2bf(a6); gb[7] = (short)f2bf(a7);
    *(bf16x8*)(Gb + (size_t)r * DD + l4 * 8) = gb;
  }
}

// proj GEMM body (also emits e0bf).
__device__ __forceinline__ void proj_body(int b, int tid,
                                          const float* __restrict__ Au,
                                          const float* __restrict__ Ai,
                                          const u16* __restrict__ BTu,
                                          const u16* __restrict__ BTi,
                                          u16* __restrict__ uuHb,
                                          u16* __restrict__ e0bf) {
  bool usr = b < NBU_M;
  const float* A = usr ? Au : Ai;
  const u16* BT = usr ? BTu : BTi;
  int n = usr ? NU : NI;
  int lb = usr ? b : b - NBU_M;
  int gbase = usr ? 0 : NU;

  int wv = tid >> 6, lane = tid & 63;
  int t = lane & 15, g = lane >> 4;
  int rowa = lb * 64 + wv * 16 + t;
  int ra = rowa < n ? rowa : (n - 1);
  const float* ap = A + (size_t)ra * DD;

  bf16x8 af[4];
#pragma unroll
  for (int k0 = 0; k0 < 4; ++k0) {
    float4 x = *(const float4*)(ap + k0 * 32 + g * 8);
    float4 y = *(const float4*)(ap + k0 * 32 + g * 8 + 4);
    bf16x8 v;
    v[0] = (short)f2bf(x.x); v[1] = (short)f2bf(x.y);
    v[2] = (short)f2bf(x.z); v[3] = (short)f2bf(x.w);
    v[4] = (short)f2bf(y.x); v[5] = (short)f2bf(y.y);
    v[6] = (short)f2bf(y.z); v[7] = (short)f2bf(y.w);
    af[k0] = v;
  }
  if (rowa < n) {
#pragma unroll
    for (int k0 = 0; k0 < 4; ++k0)
      *(bf16x8*)(e0bf + (size_t)(gbase + rowa) * DD + k0 * 32 + g * 8) = af[k0];
  }

  f32x4 acc[8];
#pragma unroll
  for (int cb = 0; cb < 8; ++cb) acc[cb] = (f32x4){0.f, 0.f, 0.f, 0.f};
#pragma unroll
  for (int k0 = 0; k0 < 4; ++k0)
#pragma unroll
    for (int cb = 0; cb < 8; ++cb) {
      bf16x8 bfr = *(const bf16x8*)(BT + (size_t)(cb * 16 + t) * 128 + k0 * 32 + g * 8);
      acc[cb] = __builtin_amdgcn_mfma_f32_16x16x32_bf16(af[k0], bfr, acc[cb], 0, 0, 0);
    }

  int rbase = lb * 64 + wv * 16 + g * 4;
#pragma unroll
  for (int cb = 0; cb < 8; ++cb)
#pragma unroll
    for (int j = 0; j < 4; ++j) {
      int lr = rbase + j;
      if (lr < n) uuHb[(size_t)(gbase + lr) * DD + cb * 16 + t] = f2bf(acc[cb][j]);
    }
}

// ---------------- launch 1: hist ∥ transp ----------------
__global__ __launch_bounds__(256)
void hist_transp(const int* __restrict__ rows, int* __restrict__ cnt, int E,
                 const float* __restrict__ uh, const float* __restrict__ ih,
                 u16* __restrict__ uhT, u16* __restrict__ ihT) {
  int b = blockIdx.x;
  if (b < NSC) {
    int e = b * 256 + threadIdx.x;
    if (e < E) atomicAdd(&cnt[rows[e]], 1);
    return;
  }
  const float* B = (b - NSC) ? ih : uh;
  u16* BT = (b - NSC) ? ihT : uhT;
  for (int i = threadIdx.x; i < 16384; i += 256) {
    int r = i >> 7, c = i & 127;
    BT[c * 128 + r] = f2bf(B[r * 128 + c]);
  }
}

// ---------------- launch 2: scan(1 block) ∥ proj ∥ zero-lat ----------------
__global__ __launch_bounds__(256)
void scan_proj_zero(const int* __restrict__ cnt, int* __restrict__ row_ptr,
                    const float* __restrict__ Au, const float* __restrict__ Ai,
                    const u16* __restrict__ BTu, const u16* __restrict__ BTi,
                    u16* __restrict__ uuHb, u16* __restrict__ e0bf,
                    float* __restrict__ latZ) {
  int b = blockIdx.x;
  if (b == 0) {
    // single-block full scan of cnt[0..NT) -> row_ptr[1..NT]
    __shared__ int ssum[256];
    int t = threadIdx.x;
    int lo = t * CSC, hi = min(lo + CSC, NT);
    int s = 0;
    for (int i = lo; i < hi; ++i) s += cnt[i];
    ssum[t] = s;
    __syncthreads();
#pragma unroll
    for (int off = 1; off < 256; off <<= 1) {
      int add = (t >= off) ? ssum[t - off] : 0;
      __syncthreads();
      ssum[t] += add;
      __syncthreads();
    }
    int run = t ? ssum[t - 1] : 0;
    for (int i = lo; i < hi; ++i) { run += cnt[i]; row_ptr[i + 1] = run; }
    if (t == 0) row_ptr[0] = 0;
    return;
  }
  if (b > NBM) {
    int zb = b - NBM - 1;
    int base = (zb * 256 + threadIdx.x) * 16;
    f32x4 z = {0.f, 0.f, 0.f, 0.f};
#pragma unroll
    for (int j = 0; j < 4; ++j) *(f32x4*)(latZ + base + j * 4) = z;
    return;
  }
  proj_body(b - 1, threadIdx.x, Au, Ai, BTu, BTi, uuHb, e0bf);
}

// ---------------- launch 3: tn(layer0) ∥ scatter ----------------
__global__ __launch_bounds__(256)
void tn_scatter(const u16* __restrict__ Ab, const u16* __restrict__ e0bf,
                float* __restrict__ latU, float* __restrict__ latI,
                const int* __restrict__ rows, const int* __restrict__ cols,
                const float* __restrict__ vals, const int* __restrict__ row_ptr,
                int* __restrict__ cursor, int2* __restrict__ sedge, int E) {
  __shared__ u32 ATs[1024];
  __shared__ u32 BTs[1024];
  int b = blockIdx.x;
  if (b < NB_TN4) {
    tn_body(b, threadIdx.x, Ab, e0bf, latU, latI, ATs, BTs);
    return;
  }
  int e = (b - NB_TN4) * 256 + threadIdx.x;
  if (e >= E) return;
  int r = rows[e];
  int p = row_ptr[r] + atomicAdd(&cursor[r], 1);
  int2 ev; ev.x = cols[e]; ev.y = __float_as_int(vals[e]);
  sedge[p] = ev;
}

// ---------------- launch 4: vg1 ∥ spmm(layer0) ----------------
__global__ __launch_bounds__(256)
void vg1_spmm(const float* __restrict__ V, const float* __restrict__ inU,
              const float* __restrict__ inI, float* __restrict__ outU,
              float* __restrict__ outI,
              const int* __restrict__ rp, const int2* __restrict__ se,
              const u16* __restrict__ pb, float* __restrict__ G,
              u16* __restrict__ Gb) {
  int b = blockIdx.x;
  if (b < 32) {
    const float* in = b < 16 ? inU : inI;
    float* outp = b < 16 ? outU : outI;
    int row = (b & 15) * 8 + (threadIdx.x >> 5);
    int c4 = (threadIdx.x & 31) * 4;
    float4 acc = make_float4(0.f, 0.f, 0.f, 0.f);
    for (int k = 0; k < 128; ++k) {
      float v = V[row * 128 + k];
      float4 l = *(const float4*)(in + k * 128 + c4);
      l.x = lrelu(l.x); l.y = lrelu(l.y); l.z = lrelu(l.z); l.w = lrelu(l.w);
      acc.x = fmaf(v, l.x, acc.x);
      acc.y = fmaf(v, l.y, acc.y);
      acc.z = fmaf(v, l.z, acc.z);
      acc.w = fmaf(v, l.w, acc.w);
    }
    float4 r = *(const float4*)(in + row * 128 + c4);
    float4 o;
    o.x = lrelu(acc.x) + lrelu(r.x);
    o.y = lrelu(acc.y) + lrelu(r.y);
    o.z = lrelu(acc.z) + lrelu(r.z);
    o.w = lrelu(acc.w) + lrelu(r.w);
    *(float4*)(outp + row * 128 + c4) = o;
    return;
  }
  int r = (b - 32) * 4 + (threadIdx.x >> 6);
  spmm_body(r, threadIdx.x, rp, se, pb, G, Gb);
}

// plain vg1 (layer 1)
__global__ __launch_bounds__(256)
void vg1_k(const float* __restrict__ V, const float* __restrict__ inU,
           const float* __restrict__ inI, float* __restrict__ outU,
           float* __restrict__ outI) {
  const float* in = blockIdx.x < 16 ? inU : inI;
  float* outp = blockIdx.x < 16 ? outU : outI;
  int row = (blockIdx.x & 15) * 8 + (threadIdx.x >> 5);
  int c4 = (threadIdx.x & 31) * 4;
  float4 acc = make_float4(0.f, 0.f, 0.f, 0.f);
  for (int k = 0; k < 128; ++k) {
    float v = V[row * 128 + k];
    float4 l = *(const float4*)(in + k * 128 + c4);
    l.x = lrelu(l.x); l.y = lrelu(l.y); l.z = lrelu(l.z); l.w = lrelu(l.w);
    acc.x = fmaf(v, l.x, acc.x);
    acc.y = fmaf(v, l.y, acc.y);
    acc.z = fmaf(v, l.z, acc.z);
    acc.w = fmaf(v, l.w, acc.w);
  }
  float4 r = *(const float4*)(in + row * 128 + c4);
  float4 o;
  o.x = lrelu(acc.x) + lrelu(r.x);
  o.y = lrelu(acc.y) + lrelu(r.y);
  o.z = lrelu(acc.z) + lrelu(r.z);
  o.w = lrelu(acc.w) + lrelu(r.w);
  *(float4*)(outp + row * 128 + c4) = o;
}

// vg2 + zero-lat
__global__ __launch_bounds__(256)
void vg2_zero(const float* __restrict__ V, const float* __restrict__ inU,
              const float* __restrict__ inI, u16* __restrict__ outU,
              u16* __restrict__ outI, float* __restrict__ latZ) {
  if (blockIdx.x >= 32) {
    int zb = blockIdx.x - 32;
    int base = (zb * 256 + threadIdx.x) * 16;
    f32x4 z = {0.f, 0.f, 0.f, 0.f};
#pragma unroll
    for (int j = 0; j < 4; ++j) *(f32x4*)(latZ + base + j * 4) = z;
    return;
  }
  const float* in = blockIdx.x < 16 ? inU : inI;
  u16* BT = blockIdx.x < 16 ? outU : outI;
  int row = (blockIdx.x & 15) * 8 + (threadIdx.x >> 5);
  int c4 = (threadIdx.x & 31) * 4;
  float4 acc = make_float4(0.f, 0.f, 0.f, 0.f);
  for (int k = 0; k < 128; ++k) {
    float v = V[row * 128 + k];
    float4 l = *(const float4*)(in + k * 128 + c4);
    acc.x = fmaf(v, l.x, acc.x);
    acc.y = fmaf(v, l.y, acc.y);
    acc.z = fmaf(v, l.z, acc.z);
    acc.w = fmaf(v, l.w, acc.w);
  }
  float4 r = *(const float4*)(in + row * 128 + c4);
  BT[(size_t)(c4 + 0) * 128 + row] = f2bf(lrelu(acc.x) + r.x);
  BT[(size_t)(c4 + 1) * 128 + row] = f2bf(lrelu(acc.y) + r.y);
  BT[(size_t)(c4 + 2) * 128 + row] = f2bf(lrelu(acc.z) + r.z);
  BT[(size_t)(c4 + 3) * 128 + row] = f2bf(lrelu(acc.w) + r.w);
}

// layer-1 fused: tn ∥ spmm on prevb
__global__ __launch_bounds__(256)
void layer_fused(const int* __restrict__ rp, const int2* __restrict__ se,
                 const u16* __restrict__ pb, float* __restrict__ G,
                 u16* __restrict__ Gb, const u16* __restrict__ Ab,
                 float* __restrict__ latU, float* __restrict__ latI) {
  __shared__ u32 ATs[1024];
  __shared__ u32 BTs[1024];
  int b = blockIdx.x;
  if (b < NB_TN4) {
    tn_body(b, threadIdx.x, Ab, pb, latU, latI, ATs, BTs);
    return;
  }
  int r = (b - NB_TN4) * 4 + (threadIdx.x >> 6);
  spmm_body(r, threadIdx.x, rp, se, pb, G, Gb);
}

// hyper GEMM + fused epilogue
template<int LAYER>
__global__ __launch_bounds__(256)
void hyp_mfma(const u16* __restrict__ Ab,
              const u16* __restrict__ BTu, const u16* __restrict__ BTi,
              const u16* __restrict__ Gb, u16* __restrict__ prevb,
              const u16* __restrict__ e0bf,
              float* __restrict__ H, float* __restrict__ out) {
  int b = blockIdx.x;
  bool usr = b < NBU_M;
  const u16* BT = usr ? BTu : BTi;
  int n = usr ? NU : NI;
  int lb = usr ? b : b - NBU_M;
  int gbase = usr ? 0 : NU;

  int wv = threadIdx.x >> 6, lane = threadIdx.x & 63;
  int t = lane & 15, g = lane >> 4;
  int rowa = lb * 64 + wv * 16 + t;
  int ra = rowa < n ? rowa : (n - 1);
  const u16* ap = Ab + (size_t)(gbase + ra) * DD;

  bf16x8 af[4];
#pragma unroll
  for (int k0 = 0; k0 < 4; ++k0)
    af[k0] = *(const bf16x8*)(ap + k0 * 32 + g * 8);

  f32x4 acc[8];
#pragma unroll
  for (int cb = 0; cb < 8; ++cb) acc[cb] = (f32x4){0.f, 0.f, 0.f, 0.f};
#pragma unroll
  for (int k0 = 0; k0 < 4; ++k0)
#pragma unroll
    for (int cb = 0; cb < 8; ++cb) {
      bf16x8 bfr = *(const bf16x8*)(BT + (size_t)(cb * 16 + t) * 128 + k0 * 32 + g * 8);
      acc[cb] = __builtin_amdgcn_mfma_f32_16x16x32_bf16(af[k0], bfr, acc[cb], 0, 0, 0);
    }

  int rbase = lb * 64 + wv * 16 + g * 4;
#pragma unroll
  for (int cb = 0; cb < 8; ++cb)
#pragma unroll
    for (int j = 0; j < 4; ++j) {
      int lr = rbase + j;
      if (lr < n) {
        size_t gi = (size_t)(gbase + lr) * DD + cb * 16 + t;
        float h = lrelu(acc[cb][j]);
        float gv = bf1(Gb[gi]);
        H[gi] = h;
        if (LAYER == 0) {
          prevb[gi] = f2bf(gv + h);
        } else {
          out[gi] = bf1(e0bf[gi]) + bf1(prevb[gi]) + gv + h;
        }
      }
    }
}

extern "C" void kernel_launch(void* const* d_in, const int* in_sizes, int n_in,
                              void* d_out, int out_size, void* d_ws, size_t ws_size,
                              hipStream_t stream) {
  const float* u_emb = (const float*)d_in[0];
  const float* i_emb = (const float*)d_in[1];
  const float* u_hyp = (const float*)d_in[2];
  const float* i_hyp = (const float*)d_in[3];
  const float* Vm    = (const float*)d_in[4];
  const int*   rows  = (const int*)d_in[5];
  const int*   cols  = (const int*)d_in[6];
  const float* vals  = (const float*)d_in[7];
  int E = in_sizes[5];

  float* out = (float*)d_out;
  float* OUT_G = out + (size_t)NT * DD;        // gnn_lats [2,N,D]
  float* OUT_H = out + (size_t)3 * NT * DD;    // hyper_lats [2,N,D]

  char* w = (char*)d_ws;
  u16* uuHb   = (u16*)w;              w += (size_t)NT * DD * 2;
  u16* e0bf   = (u16*)w;              w += (size_t)NT * DD * 2;
  u16* prevb  = (u16*)w;              w += (size_t)NT * DD * 2;
  u16* Gb     = (u16*)w;              w += (size_t)NT * DD * 2;
  float* latU = (float*)w;            w += 16384 * 4;
  float* latI = (float*)w;            w += 16384 * 4;   // contiguous with latU
  float* lat2U = (float*)w;           w += 16384 * 4;
  float* lat2I = (float*)w;           w += 16384 * 4;
  u16* uhT    = (u16*)w;              w += 16384 * 2;
  u16* ihT    = (u16*)w;              w += 16384 * 2;
  u16* latTu  = (u16*)w;              w += 16384 * 2;
  u16* latTi  = (u16*)w;              w += 16384 * 2;
  int* row_cnt = (int*)w;             w += (size_t)NT * 4;
  int* cursor  = (int*)w;             w += (size_t)NT * 4;  // contiguous with row_cnt
  int* row_ptr = (int*)w;             w += (size_t)(NT + 1) * 4;
  int2* sedge  = (int2*)w;            w += (size_t)EDG * 8;

  float* G0 = OUT_G;
  float* G1 = OUT_G + (size_t)NT * DD;
  float* H0 = OUT_H;
  float* H1 = OUT_H + (size_t)NT * DD;

  // L0: zero row_cnt + cursor
  hipMemsetAsync(row_cnt, 0, sizeof(int) * 2 * NT, stream);
  // L1: hist ∥ transp
  hist_transp<<<NSC + 2, 256, 0, stream>>>(rows, row_cnt, E, u_hyp, i_hyp, uhT, ihT);
  // L2: scan ∥ proj ∥ zero-lat
  scan_proj_zero<<<1 + NBM + 8, 256, 0, stream>>>(
      row_cnt, row_ptr, u_emb, i_emb, uhT, ihT, uuHb, e0bf, latU);
  // L3: tn(layer0) ∥ scatter
  tn_scatter<<<NB_TN4 + NSC, 256, 0, stream>>>(
      uuHb, e0bf, latU, latI, rows, cols, vals, row_ptr, cursor, sedge, E);
  // L4: vg1 ∥ spmm(layer0)
  vg1_spmm<<<32 + NSPMM, 256, 0, stream>>>(
      Vm, latU, latI, lat2U, lat2I, row_ptr, sedge, e0bf, G0, Gb);
  // L5: vg2 ∥ zero-lat (for layer 1)
  vg2_zero<<<40, 256, 0, stream>>>(Vm, lat2U, lat2I, latTu, latTi, latU);
  // L6: hyp<0>  (H0, prevb)
  hyp_mfma<0><<<NBM, 256, 0, stream>>>(
      uuHb, latTu, latTi, Gb, prevb, e0bf, H0, out);
  // L7: layer-1 tn ∥ spmm on prevb
  layer_fused<<<NB_TN4 + NSPMM, 256, 0, stream>>>(
      row_ptr, sedge, prevb, G1, Gb, uuHb, latU, latI);
  // L8: vg1
  vg1_k<<<32, 256, 0, stream>>>(Vm, latU, latI, lat2U, lat2I);
  // L9: vg2 (zero part harmless)
  vg2_zero<<<40, 256, 0, stream>>>(Vm, lat2U, lat2I, latTu, latTi, latU);
  // L10: hyp<1>  (H1, out)
  hyp_mfma<1><<<NBM, 256, 0, stream>>>(
      uuHb, latTu, latTi, Gb, prevb, e0bf, H1, out);
}

// Round 13
// 542.411 us; speedup vs baseline: 1.3316x; 1.3316x over previous
//
#include <hip/hip_runtime.h>

#define NU 50000
#define NI 70000
#define NT 120000
#define DD 128
#define EDG 800000
#define NCH ((NT + 255) / 256)      // 469 scan chunks
#define CHK 256                     // tn row chunk
#define NBU_TN ((NU + CHK - 1) / CHK)   // 196
#define NBI_TN ((NI + CHK - 1) / CHK)   // 274
#define NB_TN4 (4 * (NBU_TN + NBI_TN))  // 1880 (64x64 quadrant blocks)
#define NBU_M ((NU + 63) / 64)      // 782
#define NBI_M ((NI + 63) / 64)      // 1094
#define NBM (NBU_M + NBI_M)         // 1876
#define NSC ((EDG + 255) / 256)     // 3125 scatter/hist blocks
#define NSPMM (NT / 4)              // 30000 spmm blocks
#define SLOPE 0.5f

typedef __attribute__((ext_vector_type(8))) short bf16x8;
typedef __attribute__((ext_vector_type(4))) float f32x4;
typedef unsigned short u16;
typedef unsigned int u32;

__device__ __forceinline__ float lrelu(float x) { return x >= 0.f ? x : SLOPE * x; }

__device__ __forceinline__ u16 f2bf(float x) {
  union { float f; u32 u; } t; t.f = x;
  u32 r = (t.u + 0x7fffu + ((t.u >> 16) & 1u)) >> 16;
  return (u16)r;
}
__device__ __forceinline__ float bflo(u32 u) {
  union { u32 u; float f; } t; t.u = u << 16; return t.f;
}
__device__ __forceinline__ float bfhi(u32 u) {
  union { u32 u; float f; } t; t.u = u & 0xffff0000u; return t.f;
}
__device__ __forceinline__ float bf1(u16 u) {
  union { u32 u; float f; } t; t.u = (u32)u << 16; return t.f;
}

// ---------------- shared device bodies ----------------

__device__ __forceinline__ void tn_body(int b, int tid,
                                        const u16* __restrict__ Ab,
                                        const u16* __restrict__ pb,
                                        float* __restrict__ latU,
                                        float* __restrict__ latI,
                                        u32* ATs, u32* BTs) {
  int quad = b & 3, cb = b >> 2;
  bool usr = cb < NBU_TN;
  int n = usr ? NU : NI;
  int gbase = usr ? 0 : NU;
  float* outp = usr ? latU : latI;
  int r0c = (usr ? cb : cb - NBU_TN) * CHK;
  int r1c = min(r0c + CHK, n);
  int hh = (quad >> 1) * 64, dh = (quad & 1) * 64;

  int rp2 = tid & 15;
  int sg = tid >> 4;
  int wv = tid >> 6, lane = tid & 63;
  int t = lane & 15, g = lane >> 4;
  int wr = wv >> 1, wc = wv & 1;

  f32x4 acc[2][2];
#pragma unroll
  for (int a = 0; a < 2; ++a)
#pragma unroll
    for (int c2 = 0; c2 < 2; ++c2) acc[a][c2] = (f32x4){0.f, 0.f, 0.f, 0.f};

  for (int r0 = r0c; r0 < r1c; r0 += 32) {
    int ra = r0 + 2 * rp2, rb2 = ra + 1;
    uint2 a0 = {0,0}, a1 = {0,0}, b0 = {0,0}, b1 = {0,0};
    if (ra < r1c) {
      a0 = *(const uint2*)(Ab + (size_t)(gbase + ra) * DD + hh + sg * 4);
      b0 = *(const uint2*)(pb + (size_t)(gbase + ra) * DD + dh + sg * 4);
    }
    if (rb2 < r1c) {
      a1 = *(const uint2*)(Ab + (size_t)(gbase + rb2) * DD + hh + sg * 4);
      b1 = *(const uint2*)(pb + (size_t)(gbase + rb2) * DD + dh + sg * 4);
    }
    __syncthreads();
#pragma unroll
    for (int j = 0; j < 4; ++j) {
      u32 alo = ((const u32*)&a0)[j >> 1], ahi = ((const u32*)&a1)[j >> 1];
      u32 blo = ((const u32*)&b0)[j >> 1], bhi = ((const u32*)&b1)[j >> 1];
      u32 wa, wb;
      if (j & 1) {
        wa = (alo >> 16) | (ahi & 0xffff0000u);
        wb = (blo >> 16) | (bhi & 0xffff0000u);
      } else {
        wa = (alo & 0xffffu) | (ahi << 16);
        wb = (blo & 0xffffu) | (bhi << 16);
      }
      int c = sg * 4 + j;
      int idx = c * 16 + (rp2 ^ ((c & 3) << 2));
      ATs[idx] = wa;
      BTs[idx] = wb;
    }
    __syncthreads();

    bf16x8 afr[2], bfr[2];
#pragma unroll
    for (int a = 0; a < 2; ++a) {
      int c = wr * 32 + a * 16 + t;
      afr[a] = *(const bf16x8*)&ATs[c * 16 + ((g ^ (c & 3)) << 2)];
    }
#pragma unroll
    for (int c2 = 0; c2 < 2; ++c2) {
      int c = wc * 32 + c2 * 16 + t;
      bfr[c2] = *(const bf16x8*)&BTs[c * 16 + ((g ^ (c & 3)) << 2)];
    }
#pragma unroll
    for (int a = 0; a < 2; ++a)
#pragma unroll
      for (int c2 = 0; c2 < 2; ++c2)
        acc[a][c2] = __builtin_amdgcn_mfma_f32_16x16x32_bf16(
            afr[a], bfr[c2], acc[a][c2], 0, 0, 0);
  }

#pragma unroll
  for (int a = 0; a < 2; ++a) {
    int h = hh + wr * 32 + a * 16 + g * 4;
#pragma unroll
    for (int c2 = 0; c2 < 2; ++c2) {
      int d = dh + wc * 32 + c2 * 16 + t;
#pragma unroll
      for (int j = 0; j < 4; ++j)
        atomicAdd(outp + (h + j) * 128 + d, acc[a][c2][j]);
    }
  }
}

__device__ __forceinline__ void spmm_body(int r, int tid,
                                          const int* __restrict__ rp,
                                          const int2* __restrict__ se,
                                          const u16* __restrict__ pb,
                                          float* __restrict__ G,
                                          u16* __restrict__ Gb) {
  int lane = tid & 63;
  int p0 = rp[r], p1 = rp[r + 1];
  int q = lane >> 4, l4 = lane & 15;
  float a0 = 0.f, a1 = 0.f, a2 = 0.f, a3 = 0.f;
  float a4 = 0.f, a5 = 0.f, a6 = 0.f, a7 = 0.f;
  int p = p0 + q;
  for (; p + 4 < p1; p += 8) {
    int2 e1 = se[p];
    int2 e2 = se[p + 4];
    uint4 u1 = *(const uint4*)(pb + (size_t)e1.x * DD + l4 * 8);
    uint4 u2 = *(const uint4*)(pb + (size_t)e2.x * DD + l4 * 8);
    float v1 = __int_as_float(e1.y), v2 = __int_as_float(e2.y);
    a0 = fmaf(v1, bflo(u1.x), a0); a1 = fmaf(v1, bfhi(u1.x), a1);
    a2 = fmaf(v1, bflo(u1.y), a2); a3 = fmaf(v1, bfhi(u1.y), a3);
    a4 = fmaf(v1, bflo(u1.z), a4); a5 = fmaf(v1, bfhi(u1.z), a5);
    a6 = fmaf(v1, bflo(u1.w), a6); a7 = fmaf(v1, bfhi(u1.w), a7);
    a0 = fmaf(v2, bflo(u2.x), a0); a1 = fmaf(v2, bfhi(u2.x), a1);
    a2 = fmaf(v2, bflo(u2.y), a2); a3 = fmaf(v2, bfhi(u2.y), a3);
    a4 = fmaf(v2, bflo(u2.z), a4); a5 = fmaf(v2, bfhi(u2.z), a5);
    a6 = fmaf(v2, bflo(u2.w), a6); a7 = fmaf(v2, bfhi(u2.w), a7);
  }
  if (p < p1) {
    int2 e1 = se[p];
    uint4 u1 = *(const uint4*)(pb + (size_t)e1.x * DD + l4 * 8);
    float v1 = __int_as_float(e1.y);
    a0 = fmaf(v1, bflo(u1.x), a0); a1 = fmaf(v1, bfhi(u1.x), a1);
    a2 = fmaf(v1, bflo(u1.y), a2); a3 = fmaf(v1, bfhi(u1.y), a3);
    a4 = fmaf(v1, bflo(u1.z), a4); a5 = fmaf(v1, bfhi(u1.z), a5);
    a6 = fmaf(v1, bflo(u1.w), a6); a7 = fmaf(v1, bfhi(u1.w), a7);
  }
  a0 += __shfl_xor(a0, 16, 64); a0 += __shfl_xor(a0, 32, 64);
  a1 += __shfl_xor(a1, 16, 64); a1 += __shfl_xor(a1, 32, 64);
  a2 += __shfl_xor(a2, 16, 64); a2 += __shfl_xor(a2, 32, 64);
  a3 += __shfl_xor(a3, 16, 64); a3 += __shfl_xor(a3, 32, 64);
  a4 += __shfl_xor(a4, 16, 64); a4 += __shfl_xor(a4, 32, 64);
  a5 += __shfl_xor(a5, 16, 64); a5 += __shfl_xor(a5, 32, 64);
  a6 += __shfl_xor(a6, 16, 64); a6 += __shfl_xor(a6, 32, 64);
  a7 += __shfl_xor(a7, 16, 64); a7 += __shfl_xor(a7, 32, 64);
  if (q == 0) {
    a0 = lrelu(a0); a1 = lrelu(a1); a2 = lrelu(a2); a3 = lrelu(a3);
    a4 = lrelu(a4); a5 = lrelu(a5); a6 = lrelu(a6); a7 = lrelu(a7);
    float4 o1, o2;
    o1.x = a0; o1.y = a1; o1.z = a2; o1.w = a3;
    o2.x = a4; o2.y = a5; o2.z = a6; o2.w = a7;
    *(float4*)(G + (size_t)r * DD + l4 * 8) = o1;
    *(float4*)(G + (size_t)r * DD + l4 * 8 + 4) = o2;
    bf16x8 gb;
    gb[0] = (short)f2bf(a0); gb[1] = (short)f2bf(a1);
    gb[2] = (short)f2bf(a2); gb[3] = (short)f2bf(a3);
    gb[4] = (short)f2bf(a4); gb[5] = (short)f2bf(a5);
    gb[6] = (short)f2bf(a6); gb[7] = (short)f2bf(a7);
    *(bf16x8*)(Gb + (size_t)r * DD + l4 * 8) = gb;
  }
}

__device__ __forceinline__ void proj_body(int b, int tid,
                                          const float* __restrict__ Au,
                                          const float* __restrict__ Ai,
                                          const u16* __restrict__ BTu,
                                          const u16* __restrict__ BTi,
                                          u16* __restrict__ uuHb,
                                          u16* __restrict__ e0bf) {
  bool usr = b < NBU_M;
  const float* A = usr ? Au : Ai;
  const u16* BT = usr ? BTu : BTi;
  int n = usr ? NU : NI;
  int lb = usr ? b : b - NBU_M;
  int gbase = usr ? 0 : NU;

  int wv = tid >> 6, lane = tid & 63;
  int t = lane & 15, g = lane >> 4;
  int rowa = lb * 64 + wv * 16 + t;
  int ra = rowa < n ? rowa : (n - 1);
  const float* ap = A + (size_t)ra * DD;

  bf16x8 af[4];
#pragma unroll
  for (int k0 = 0; k0 < 4; ++k0) {
    float4 x = *(const float4*)(ap + k0 * 32 + g * 8);
    float4 y = *(const float4*)(ap + k0 * 32 + g * 8 + 4);
    bf16x8 v;
    v[0] = (short)f2bf(x.x); v[1] = (short)f2bf(x.y);
    v[2] = (short)f2bf(x.z); v[3] = (short)f2bf(x.w);
    v[4] = (short)f2bf(y.x); v[5] = (short)f2bf(y.y);
    v[6] = (short)f2bf(y.z); v[7] = (short)f2bf(y.w);
    af[k0] = v;
  }
  if (rowa < n) {
#pragma unroll
    for (int k0 = 0; k0 < 4; ++k0)
      *(bf16x8*)(e0bf + (size_t)(gbase + rowa) * DD + k0 * 32 + g * 8) = af[k0];
  }

  f32x4 acc[8];
#pragma unroll
  for (int cb = 0; cb < 8; ++cb) acc[cb] = (f32x4){0.f, 0.f, 0.f, 0.f};
#pragma unroll
  for (int k0 = 0; k0 < 4; ++k0)
#pragma unroll
    for (int cb = 0; cb < 8; ++cb) {
      bf16x8 bfr = *(const bf16x8*)(BT + (size_t)(cb * 16 + t) * 128 + k0 * 32 + g * 8);
      acc[cb] = __builtin_amdgcn_mfma_f32_16x16x32_bf16(af[k0], bfr, acc[cb], 0, 0, 0);
    }

  int rbase = lb * 64 + wv * 16 + g * 4;
#pragma unroll
  for (int cb = 0; cb < 8; ++cb)
#pragma unroll
    for (int j = 0; j < 4; ++j) {
      int lr = rbase + j;
      if (lr < n) uuHb[(size_t)(gbase + lr) * DD + cb * 16 + t] = f2bf(acc[cb][j]);
    }
}

// ---------------- L1: hist ∥ transp ----------------
__global__ __launch_bounds__(256)
void hist_transp(const int* __restrict__ rows, int* __restrict__ cnt, int E,
                 const float* __restrict__ uh, const float* __restrict__ ih,
                 u16* __restrict__ uhT, u16* __restrict__ ihT) {
  int b = blockIdx.x;
  if (b < NSC) {
    int e = b * 256 + threadIdx.x;
    if (e < E) atomicAdd(&cnt[rows[e]], 1);
    return;
  }
  const float* B = (b - NSC) ? ih : uh;
  u16* BT = (b - NSC) ? ihT : uhT;
  for (int i = threadIdx.x; i < 16384; i += 256) {
    int r = i >> 7, c = i & 127;
    BT[c * 128 + r] = f2bf(B[r * 128 + c]);
  }
}

// ---------------- L2/L3: multi-block scan (proven R11 path) ----------------
__global__ __launch_bounds__(256)
void scan1_k(const int* __restrict__ cnt, int* __restrict__ tmp, int* __restrict__ part) {
  __shared__ int s[256];
  int gid = blockIdx.x * 256 + threadIdx.x;
  s[threadIdx.x] = (gid < NT) ? cnt[gid] : 0;
  __syncthreads();
#pragma unroll
  for (int off = 1; off < 256; off <<= 1) {
    int add = (threadIdx.x >= off) ? s[threadIdx.x - off] : 0;
    __syncthreads();
    s[threadIdx.x] += add;
    __syncthreads();
  }
  if (gid < NT) tmp[gid] = s[threadIdx.x];
  if (threadIdx.x == 255) part[blockIdx.x] = s[255];
}

__global__ __launch_bounds__(512)
void scan2_k(int* __restrict__ part) {
  __shared__ int s[512];
  s[threadIdx.x] = (threadIdx.x < NCH) ? part[threadIdx.x] : 0;
  __syncthreads();
#pragma unroll
  for (int off = 1; off < 512; off <<= 1) {
    int add = (threadIdx.x >= off) ? s[threadIdx.x - off] : 0;
    __syncthreads();
    s[threadIdx.x] += add;
    __syncthreads();
  }
  if (threadIdx.x < NCH) part[threadIdx.x] = s[threadIdx.x];
}

// ---------------- L4: scan3 ∥ proj ∥ zero-lat ----------------
__global__ __launch_bounds__(256)
void scan3_proj_zero(const int* __restrict__ tmp, const int* __restrict__ part,
                     int* __restrict__ row_ptr,
                     const float* __restrict__ Au, const float* __restrict__ Ai,
                     const u16* __restrict__ BTu, const u16* __restrict__ BTi,
                     u16* __restrict__ uuHb, u16* __restrict__ e0bf,
                     float* __restrict__ latZ) {
  int b = blockIdx.x;
  if (b < NCH) {
    int gid = b * 256 + threadIdx.x;
    if (gid < NT) {
      int off = b ? part[b - 1] : 0;
      row_ptr[gid + 1] = tmp[gid] + off;
    }
    if (gid == 0) row_ptr[0] = 0;
    return;
  }
  if (b >= NCH + NBM) {
    int zb = b - NCH - NBM;
    int base = (zb * 256 + threadIdx.x) * 16;
    f32x4 z = {0.f, 0.f, 0.f, 0.f};
#pragma unroll
    for (int j = 0; j < 4; ++j) *(f32x4*)(latZ + base + j * 4) = z;
    return;
  }
  proj_body(b - NCH, threadIdx.x, Au, Ai, BTu, BTi, uuHb, e0bf);
}

// ---------------- L5: tn(layer0) ∥ scatter ----------------
__global__ __launch_bounds__(256)
void tn_scatter(const u16* __restrict__ Ab, const u16* __restrict__ e0bf,
                float* __restrict__ latU, float* __restrict__ latI,
                const int* __restrict__ rows, const int* __restrict__ cols,
                const float* __restrict__ vals, const int* __restrict__ row_ptr,
                int* __restrict__ cursor, int2* __restrict__ sedge, int E) {
  __shared__ u32 ATs[1024];
  __shared__ u32 BTs[1024];
  int b = blockIdx.x;
  if (b < NB_TN4) {
    tn_body(b, threadIdx.x, Ab, e0bf, latU, latI, ATs, BTs);
    return;
  }
  int e = (b - NB_TN4) * 256 + threadIdx.x;
  if (e >= E) return;
  int r = rows[e];
  int p = row_ptr[r] + atomicAdd(&cursor[r], 1);
  int2 ev; ev.x = cols[e]; ev.y = __float_as_int(vals[e]);
  sedge[p] = ev;
}

// ---------------- L6: vg1 ∥ spmm(layer0) ----------------
__global__ __launch_bounds__(256)
void vg1_spmm(const float* __restrict__ V, const float* __restrict__ inU,
              const float* __restrict__ inI, float* __restrict__ outU,
              float* __restrict__ outI,
              const int* __restrict__ rp, const int2* __restrict__ se,
              const u16* __restrict__ pb, float* __restrict__ G,
              u16* __restrict__ Gb) {
  int b = blockIdx.x;
  if (b < 32) {
    const float* in = b < 16 ? inU : inI;
    float* outp = b < 16 ? outU : outI;
    int row = (b & 15) * 8 + (threadIdx.x >> 5);
    int c4 = (threadIdx.x & 31) * 4;
    float4 acc = make_float4(0.f, 0.f, 0.f, 0.f);
    for (int k = 0; k < 128; ++k) {
      float v = V[row * 128 + k];
      float4 l = *(const float4*)(in + k * 128 + c4);
      l.x = lrelu(l.x); l.y = lrelu(l.y); l.z = lrelu(l.z); l.w = lrelu(l.w);
      acc.x = fmaf(v, l.x, acc.x);
      acc.y = fmaf(v, l.y, acc.y);
      acc.z = fmaf(v, l.z, acc.z);
      acc.w = fmaf(v, l.w, acc.w);
    }
    float4 r = *(const float4*)(in + row * 128 + c4);
    float4 o;
    o.x = lrelu(acc.x) + lrelu(r.x);
    o.y = lrelu(acc.y) + lrelu(r.y);
    o.z = lrelu(acc.z) + lrelu(r.z);
    o.w = lrelu(acc.w) + lrelu(r.w);
    *(float4*)(outp + row * 128 + c4) = o;
    return;
  }
  int r = (b - 32) * 4 + (threadIdx.x >> 6);
  spmm_body(r, threadIdx.x, rp, se, pb, G, Gb);
}

// plain vg1 (layer 1)
__global__ __launch_bounds__(256)
void vg1_k(const float* __restrict__ V, const float* __restrict__ inU,
           const float* __restrict__ inI, float* __restrict__ outU,
           float* __restrict__ outI) {
  const float* in = blockIdx.x < 16 ? inU : inI;
  float* outp = blockIdx.x < 16 ? outU : outI;
  int row = (blockIdx.x & 15) * 8 + (threadIdx.x >> 5);
  int c4 = (threadIdx.x & 31) * 4;
  float4 acc = make_float4(0.f, 0.f, 0.f, 0.f);
  for (int k = 0; k < 128; ++k) {
    float v = V[row * 128 + k];
    float4 l = *(const float4*)(in + k * 128 + c4);
    l.x = lrelu(l.x); l.y = lrelu(l.y); l.z = lrelu(l.z); l.w = lrelu(l.w);
    acc.x = fmaf(v, l.x, acc.x);
    acc.y = fmaf(v, l.y, acc.y);
    acc.z = fmaf(v, l.z, acc.z);
    acc.w = fmaf(v, l.w, acc.w);
  }
  float4 r = *(const float4*)(in + row * 128 + c4);
  float4 o;
  o.x = lrelu(acc.x) + lrelu(r.x);
  o.y = lrelu(acc.y) + lrelu(r.y);
  o.z = lrelu(acc.z) + lrelu(r.z);
  o.w = lrelu(acc.w) + lrelu(r.w);
  *(float4*)(outp + row * 128 + c4) = o;
}

// vg2 + zero-lat
__global__ __launch_bounds__(256)
void vg2_zero(const float* __restrict__ V, const float* __restrict__ inU,
              const float* __restrict__ inI, u16* __restrict__ outU,
              u16* __restrict__ outI, float* __restrict__ latZ) {
  if (blockIdx.x >= 32) {
    int zb = blockIdx.x - 32;
    int base = (zb * 256 + threadIdx.x) * 16;
    f32x4 z = {0.f, 0.f, 0.f, 0.f};
#pragma unroll
    for (int j = 0; j < 4; ++j) *(f32x4*)(latZ + base + j * 4) = z;
    return;
  }
  const float* in = blockIdx.x < 16 ? inU : inI;
  u16* BT = blockIdx.x < 16 ? outU : outI;
  int row = (blockIdx.x & 15) * 8 + (threadIdx.x >> 5);
  int c4 = (threadIdx.x & 31) * 4;
  float4 acc = make_float4(0.f, 0.f, 0.f, 0.f);
  for (int k = 0; k < 128; ++k) {
    float v = V[row * 128 + k];
    float4 l = *(const float4*)(in + k * 128 + c4);
    acc.x = fmaf(v, l.x, acc.x);
    acc.y = fmaf(v, l.y, acc.y);
    acc.z = fmaf(v, l.z, acc.z);
    acc.w = fmaf(v, l.w, acc.w);
  }
  float4 r = *(const float4*)(in + row * 128 + c4);
  BT[(size_t)(c4 + 0) * 128 + row] = f2bf(lrelu(acc.x) + r.x);
  BT[(size_t)(c4 + 1) * 128 + row] = f2bf(lrelu(acc.y) + r.y);
  BT[(size_t)(c4 + 2) * 128 + row] = f2bf(lrelu(acc.z) + r.z);
  BT[(size_t)(c4 + 3) * 128 + row] = f2bf(lrelu(acc.w) + r.w);
}

// layer-1 fused: tn ∥ spmm on prevb
__global__ __launch_bounds__(256)
void layer_fused(const int* __restrict__ rp, const int2* __restrict__ se,
                 const u16* __restrict__ pb, float* __restrict__ G,
                 u16* __restrict__ Gb, const u16* __restrict__ Ab,
                 float* __restrict__ latU, float* __restrict__ latI) {
  __shared__ u32 ATs[1024];
  __shared__ u32 BTs[1024];
  int b = blockIdx.x;
  if (b < NB_TN4) {
    tn_body(b, threadIdx.x, Ab, pb, latU, latI, ATs, BTs);
    return;
  }
  int r = (b - NB_TN4) * 4 + (threadIdx.x >> 6);
  spmm_body(r, threadIdx.x, rp, se, pb, G, Gb);
}

// hyper GEMM + fused epilogue
template<int LAYER>
__global__ __launch_bounds__(256)
void hyp_mfma(const u16* __restrict__ Ab,
              const u16* __restrict__ BTu, const u16* __restrict__ BTi,
              const u16* __restrict__ Gb, u16* __restrict__ prevb,
              const u16* __restrict__ e0bf,
              float* __restrict__ H, float* __restrict__ out) {
  int b = blockIdx.x;
  bool usr = b < NBU_M;
  const u16* BT = usr ? BTu : BTi;
  int n = usr ? NU : NI;
  int lb = usr ? b : b - NBU_M;
  int gbase = usr ? 0 : NU;

  int wv = threadIdx.x >> 6, lane = threadIdx.x & 63;
  int t = lane & 15, g = lane >> 4;
  int rowa = lb * 64 + wv * 16 + t;
  int ra = rowa < n ? rowa : (n - 1);
  const u16* ap = Ab + (size_t)(gbase + ra) * DD;

  bf16x8 af[4];
#pragma unroll
  for (int k0 = 0; k0 < 4; ++k0)
    af[k0] = *(const bf16x8*)(ap + k0 * 32 + g * 8);

  f32x4 acc[8];
#pragma unroll
  for (int cb = 0; cb < 8; ++cb) acc[cb] = (f32x4){0.f, 0.f, 0.f, 0.f};
#pragma unroll
  for (int k0 = 0; k0 < 4; ++k0)
#pragma unroll
    for (int cb = 0; cb < 8; ++cb) {
      bf16x8 bfr = *(const bf16x8*)(BT + (size_t)(cb * 16 + t) * 128 + k0 * 32 + g * 8);
      acc[cb] = __builtin_amdgcn_mfma_f32_16x16x32_bf16(af[k0], bfr, acc[cb], 0, 0, 0);
    }

  int rbase = lb * 64 + wv * 16 + g * 4;
#pragma unroll
  for (int cb = 0; cb < 8; ++cb)
#pragma unroll
    for (int j = 0; j < 4; ++j) {
      int lr = rbase + j;
      if (lr < n) {
        size_t gi = (size_t)(gbase + lr) * DD + cb * 16 + t;
        float h = lrelu(acc[cb][j]);
        float gv = bf1(Gb[gi]);
        H[gi] = h;
        if (LAYER == 0) {
          prevb[gi] = f2bf(gv + h);
        } else {
          out[gi] = bf1(e0bf[gi]) + bf1(prevb[gi]) + gv + h;
        }
      }
    }
}

extern "C" void kernel_launch(void* const* d_in, const int* in_sizes, int n_in,
                              void* d_out, int out_size, void* d_ws, size_t ws_size,
                              hipStream_t stream) {
  const float* u_emb = (const float*)d_in[0];
  const float* i_emb = (const float*)d_in[1];
  const float* u_hyp = (const float*)d_in[2];
  const float* i_hyp = (const float*)d_in[3];
  const float* Vm    = (const float*)d_in[4];
  const int*   rows  = (const int*)d_in[5];
  const int*   cols  = (const int*)d_in[6];
  const float* vals  = (const float*)d_in[7];
  int E = in_sizes[5];

  float* out = (float*)d_out;
  float* OUT_G = out + (size_t)NT * DD;        // gnn_lats [2,N,D]
  float* OUT_H = out + (size_t)3 * NT * DD;    // hyper_lats [2,N,D]

  char* w = (char*)d_ws;
  u16* uuHb   = (u16*)w;              w += (size_t)NT * DD * 2;
  u16* e0bf   = (u16*)w;              w += (size_t)NT * DD * 2;
  u16* prevb  = (u16*)w;              w += (size_t)NT * DD * 2;
  u16* Gb     = (u16*)w;              w += (size_t)NT * DD * 2;
  float* latU = (float*)w;            w += 16384 * 4;
  float* latI = (float*)w;            w += 16384 * 4;   // contiguous with latU
  float* lat2U = (float*)w;           w += 16384 * 4;
  float* lat2I = (float*)w;           w += 16384 * 4;
  u16* uhT    = (u16*)w;              w += 16384 * 2;
  u16* ihT    = (u16*)w;              w += 16384 * 2;
  u16* latTu  = (u16*)w;              w += 16384 * 2;
  u16* latTi  = (u16*)w;              w += 16384 * 2;
  int* row_cnt = (int*)w;             w += (size_t)NT * 4;
  int* cursor  = (int*)w;             w += (size_t)NT * 4;  // contiguous with row_cnt
  int* row_ptr = (int*)w;             w += (size_t)(NT + 1) * 4;
  int* tmp     = (int*)w;             w += (size_t)NT * 4;
  int* part    = (int*)w;             w += 512 * 4;
  int2* sedge  = (int2*)w;            w += (size_t)EDG * 8;

  float* G0 = OUT_G;
  float* G1 = OUT_G + (size_t)NT * DD;
  float* H0 = OUT_H;
  float* H1 = OUT_H + (size_t)NT * DD;

  // L0: zero row_cnt + cursor
  hipMemsetAsync(row_cnt, 0, sizeof(int) * 2 * NT, stream);
  // L1: hist ∥ transp
  hist_transp<<<NSC + 2, 256, 0, stream>>>(rows, row_cnt, E, u_hyp, i_hyp, uhT, ihT);
  // L2: scan1 (multi-block)
  scan1_k<<<NCH, 256, 0, stream>>>(row_cnt, tmp, part);
  // L3: scan2 (1 block over 469 partials — microseconds)
  scan2_k<<<1, 512, 0, stream>>>(part);
  // L4: scan3 ∥ proj ∥ zero-lat
  scan3_proj_zero<<<NCH + NBM + 8, 256, 0, stream>>>(
      tmp, part, row_ptr, u_emb, i_emb, uhT, ihT, uuHb, e0bf, latU);
  // L5: tn(layer0) ∥ scatter
  tn_scatter<<<NB_TN4 + NSC, 256, 0, stream>>>(
      uuHb, e0bf, latU, latI, rows, cols, vals, row_ptr, cursor, sedge, E);
  // L6: vg1 ∥ spmm(layer0)
  vg1_spmm<<<32 + NSPMM, 256, 0, stream>>>(
      Vm, latU, latI, lat2U, lat2I, row_ptr, sedge, e0bf, G0, Gb);
  // L7: vg2 ∥ zero-lat (for layer 1)
  vg2_zero<<<40, 256, 0, stream>>>(Vm, lat2U, lat2I, latTu, latTi, latU);
  // L8: hyp<0>  (H0, prevb)
  hyp_mfma<0><<<NBM, 256, 0, stream>>>(
      uuHb, latTu, latTi, Gb, prevb, e0bf, H0, out);
  // L9: layer-1 tn ∥ spmm on prevb
  layer_fused<<<NB_TN4 + NSPMM, 256, 0, stream>>>(
      row_ptr, sedge, prevb, G1, Gb, uuHb, latU, latI);
  // L10: vg1
  vg1_k<<<32, 256, 0, stream>>>(Vm, latU, latI, lat2U, lat2I);
  // L11: vg2 (zero part harmless)
  vg2_zero<<<40, 256, 0, stream>>>(Vm, lat2U, lat2I, latTu, latTi, latU);
  // L12: hyp<1>  (H1, out)
  hyp_mfma<1><<<NBM, 256, 0, stream>>>(
      uuHb, latTu, latTi, Gb, prevb, e0bf, H1, out);
}

// Round 15
// 486.287 us; speedup vs baseline: 1.4853x; 1.1154x over previous
//
#include <hip/hip_runtime.h>

#define NU 50000
#define NI 70000
#define NT 120000
#define DD 128
#define EDG 800000
#define NCH ((NT + 255) / 256)      // 469 scan chunks
#define CHK 256                     // tn row chunk
#define NBU_TN ((NU + CHK - 1) / CHK)   // 196
#define NBI_TN ((NI + CHK - 1) / CHK)   // 274
#define NB_TN4 (4 * (NBU_TN + NBI_TN))  // 1880 (64x64 quadrant blocks)
#define NBU_M ((NU + 63) / 64)      // 782
#define NBI_M ((NI + 63) / 64)      // 1094
#define NBM (NBU_M + NBI_M)         // 1876
#define NSC ((EDG + 255) / 256)     // 3125 scatter/hist blocks
#define NSPMM (NT / 4)              // 30000 spmm blocks
#define SLOPE 0.5f

typedef __attribute__((ext_vector_type(8))) short bf16x8;
typedef __attribute__((ext_vector_type(4))) float f32x4;
typedef unsigned short u16;
typedef unsigned int u32;

__device__ __forceinline__ float lrelu(float x) { return x >= 0.f ? x : SLOPE * x; }

__device__ __forceinline__ u16 f2bf(float x) {
  union { float f; u32 u; } t; t.f = x;
  u32 r = (t.u + 0x7fffu + ((t.u >> 16) & 1u)) >> 16;
  return (u16)r;
}
__device__ __forceinline__ float bflo(u32 u) {
  union { u32 u; float f; } t; t.u = u << 16; return t.f;
}
__device__ __forceinline__ float bfhi(u32 u) {
  union { u32 u; float f; } t; t.u = u & 0xffff0000u; return t.f;
}
__device__ __forceinline__ float bf1(u16 u) {
  union { u32 u; float f; } t; t.u = (u32)u << 16; return t.f;
}

// ---------------- shared device bodies ----------------

__device__ __forceinline__ void tn_body(int b, int tid,
                                        const u16* __restrict__ Ab,
                                        const u16* __restrict__ pb,
                                        float* __restrict__ latU,
                                        float* __restrict__ latI,
                                        u32* ATs, u32* BTs) {
  int quad = b & 3, cb = b >> 2;
  bool usr = cb < NBU_TN;
  int n = usr ? NU : NI;
  int gbase = usr ? 0 : NU;
  float* outp = usr ? latU : latI;
  int r0c = (usr ? cb : cb - NBU_TN) * CHK;
  int r1c = min(r0c + CHK, n);
  int hh = (quad >> 1) * 64, dh = (quad & 1) * 64;

  int rp2 = tid & 15;
  int sg = tid >> 4;
  int wv = tid >> 6, lane = tid & 63;
  int t = lane & 15, g = lane >> 4;
  int wr = wv >> 1, wc = wv & 1;

  f32x4 acc[2][2];
#pragma unroll
  for (int a = 0; a < 2; ++a)
#pragma unroll
    for (int c2 = 0; c2 < 2; ++c2) acc[a][c2] = (f32x4){0.f, 0.f, 0.f, 0.f};

  for (int r0 = r0c; r0 < r1c; r0 += 32) {
    int ra = r0 + 2 * rp2, rb2 = ra + 1;
    uint2 a0 = {0,0}, a1 = {0,0}, b0 = {0,0}, b1 = {0,0};
    if (ra < r1c) {
      a0 = *(const uint2*)(Ab + (size_t)(gbase + ra) * DD + hh + sg * 4);
      b0 = *(const uint2*)(pb + (size_t)(gbase + ra) * DD + dh + sg * 4);
    }
    if (rb2 < r1c) {
      a1 = *(const uint2*)(Ab + (size_t)(gbase + rb2) * DD + hh + sg * 4);
      b1 = *(const uint2*)(pb + (size_t)(gbase + rb2) * DD + dh + sg * 4);
    }
    __syncthreads();
#pragma unroll
    for (int j = 0; j < 4; ++j) {
      u32 alo = ((const u32*)&a0)[j >> 1], ahi = ((const u32*)&a1)[j >> 1];
      u32 blo = ((const u32*)&b0)[j >> 1], bhi = ((const u32*)&b1)[j >> 1];
      u32 wa, wb;
      if (j & 1) {
        wa = (alo >> 16) | (ahi & 0xffff0000u);
        wb = (blo >> 16) | (bhi & 0xffff0000u);
      } else {
        wa = (alo & 0xffffu) | (ahi << 16);
        wb = (blo & 0xffffu) | (bhi << 16);
      }
      int c = sg * 4 + j;
      int idx = c * 16 + (rp2 ^ ((c & 3) << 2));
      ATs[idx] = wa;
      BTs[idx] = wb;
    }
    __syncthreads();

    bf16x8 afr[2], bfr[2];
#pragma unroll
    for (int a = 0; a < 2; ++a) {
      int c = wr * 32 + a * 16 + t;
      afr[a] = *(const bf16x8*)&ATs[c * 16 + ((g ^ (c & 3)) << 2)];
    }
#pragma unroll
    for (int c2 = 0; c2 < 2; ++c2) {
      int c = wc * 32 + c2 * 16 + t;
      bfr[c2] = *(const bf16x8*)&BTs[c * 16 + ((g ^ (c & 3)) << 2)];
    }
#pragma unroll
    for (int a = 0; a < 2; ++a)
#pragma unroll
      for (int c2 = 0; c2 < 2; ++c2)
        acc[a][c2] = __builtin_amdgcn_mfma_f32_16x16x32_bf16(
            afr[a], bfr[c2], acc[a][c2], 0, 0, 0);
  }

#pragma unroll
  for (int a = 0; a < 2; ++a) {
    int h = hh + wr * 32 + a * 16 + g * 4;
#pragma unroll
    for (int c2 = 0; c2 < 2; ++c2) {
      int d = dh + wc * 32 + c2 * 16 + t;
#pragma unroll
      for (int j = 0; j < 4; ++j)
        atomicAdd(outp + (h + j) * 128 + d, acc[a][c2][j]);
    }
  }
}

__device__ __forceinline__ void spmm_body(int r, int tid,
                                          const int* __restrict__ rp,
                                          const int2* __restrict__ se,
                                          const u16* __restrict__ pb,
                                          float* __restrict__ G,
                                          u16* __restrict__ Gb) {
  int lane = tid & 63;
  int p0 = rp[r], p1 = rp[r + 1];
  int q = lane >> 4, l4 = lane & 15;
  float a0 = 0.f, a1 = 0.f, a2 = 0.f, a3 = 0.f;
  float a4 = 0.f, a5 = 0.f, a6 = 0.f, a7 = 0.f;
  int p = p0 + q;
  for (; p + 4 < p1; p += 8) {
    int2 e1 = se[p];
    int2 e2 = se[p + 4];
    uint4 u1 = *(const uint4*)(pb + (size_t)e1.x * DD + l4 * 8);
    uint4 u2 = *(const uint4*)(pb + (size_t)e2.x * DD + l4 * 8);
    float v1 = __int_as_float(e1.y), v2 = __int_as_float(e2.y);
    a0 = fmaf(v1, bflo(u1.x), a0); a1 = fmaf(v1, bfhi(u1.x), a1);
    a2 = fmaf(v1, bflo(u1.y), a2); a3 = fmaf(v1, bfhi(u1.y), a3);
    a4 = fmaf(v1, bflo(u1.z), a4); a5 = fmaf(v1, bfhi(u1.z), a5);
    a6 = fmaf(v1, bflo(u1.w), a6); a7 = fmaf(v1, bfhi(u1.w), a7);
    a0 = fmaf(v2, bflo(u2.x), a0); a1 = fmaf(v2, bfhi(u2.x), a1);
    a2 = fmaf(v2, bflo(u2.y), a2); a3 = fmaf(v2, bfhi(u2.y), a3);
    a4 = fmaf(v2, bflo(u2.z), a4); a5 = fmaf(v2, bfhi(u2.z), a5);
    a6 = fmaf(v2, bflo(u2.w), a6); a7 = fmaf(v2, bfhi(u2.w), a7);
  }
  if (p < p1) {
    int2 e1 = se[p];
    uint4 u1 = *(const uint4*)(pb + (size_t)e1.x * DD + l4 * 8);
    float v1 = __int_as_float(e1.y);
    a0 = fmaf(v1, bflo(u1.x), a0); a1 = fmaf(v1, bfhi(u1.x), a1);
    a2 = fmaf(v1, bflo(u1.y), a2); a3 = fmaf(v1, bfhi(u1.y), a3);
    a4 = fmaf(v1, bflo(u1.z), a4); a5 = fmaf(v1, bfhi(u1.z), a5);
    a6 = fmaf(v1, bflo(u1.w), a6); a7 = fmaf(v1, bfhi(u1.w), a7);
  }
  a0 += __shfl_xor(a0, 16, 64); a0 += __shfl_xor(a0, 32, 64);
  a1 += __shfl_xor(a1, 16, 64); a1 += __shfl_xor(a1, 32, 64);
  a2 += __shfl_xor(a2, 16, 64); a2 += __shfl_xor(a2, 32, 64);
  a3 += __shfl_xor(a3, 16, 64); a3 += __shfl_xor(a3, 32, 64);
  a4 += __shfl_xor(a4, 16, 64); a4 += __shfl_xor(a4, 32, 64);
  a5 += __shfl_xor(a5, 16, 64); a5 += __shfl_xor(a5, 32, 64);
  a6 += __shfl_xor(a6, 16, 64); a6 += __shfl_xor(a6, 32, 64);
  a7 += __shfl_xor(a7, 16, 64); a7 += __shfl_xor(a7, 32, 64);
  if (q == 0) {
    a0 = lrelu(a0); a1 = lrelu(a1); a2 = lrelu(a2); a3 = lrelu(a3);
    a4 = lrelu(a4); a5 = lrelu(a5); a6 = lrelu(a6); a7 = lrelu(a7);
    f32x4 o1 = {a0, a1, a2, a3};
    f32x4 o2 = {a4, a5, a6, a7};
    // G is never re-read (Gb sidecar used) — bypass caches.
    __builtin_nontemporal_store(o1, (f32x4*)(G + (size_t)r * DD + l4 * 8));
    __builtin_nontemporal_store(o2, (f32x4*)(G + (size_t)r * DD + l4 * 8 + 4));
    bf16x8 gb;
    gb[0] = (short)f2bf(a0); gb[1] = (short)f2bf(a1);
    gb[2] = (short)f2bf(a2); gb[3] = (short)f2bf(a3);
    gb[4] = (short)f2bf(a4); gb[5] = (short)f2bf(a5);
    gb[6] = (short)f2bf(a6); gb[7] = (short)f2bf(a7);
    *(bf16x8*)(Gb + (size_t)r * DD + l4 * 8) = gb;
  }
}

__device__ __forceinline__ void proj_body(int b, int tid,
                                          const float* __restrict__ Au,
                                          const float* __restrict__ Ai,
                                          const u16* __restrict__ BTu,
                                          const u16* __restrict__ BTi,
                                          u16* __restrict__ uuHb,
                                          u16* __restrict__ e0bf) {
  bool usr = b < NBU_M;
  const float* A = usr ? Au : Ai;
  const u16* BT = usr ? BTu : BTi;
  int n = usr ? NU : NI;
  int lb = usr ? b : b - NBU_M;
  int gbase = usr ? 0 : NU;

  int wv = tid >> 6, lane = tid & 63;
  int t = lane & 15, g = lane >> 4;
  int rowa = lb * 64 + wv * 16 + t;
  int ra = rowa < n ? rowa : (n - 1);
  const float* ap = A + (size_t)ra * DD;

  bf16x8 af[4];
#pragma unroll
  for (int k0 = 0; k0 < 4; ++k0) {
    float4 x = *(const float4*)(ap + k0 * 32 + g * 8);
    float4 y = *(const float4*)(ap + k0 * 32 + g * 8 + 4);
    bf16x8 v;
    v[0] = (short)f2bf(x.x); v[1] = (short)f2bf(x.y);
    v[2] = (short)f2bf(x.z); v[3] = (short)f2bf(x.w);
    v[4] = (short)f2bf(y.x); v[5] = (short)f2bf(y.y);
    v[6] = (short)f2bf(y.z); v[7] = (short)f2bf(y.w);
    af[k0] = v;
  }
  if (rowa < n) {
#pragma unroll
    for (int k0 = 0; k0 < 4; ++k0)
      *(bf16x8*)(e0bf + (size_t)(gbase + rowa) * DD + k0 * 32 + g * 8) = af[k0];
  }

  f32x4 acc[8];
#pragma unroll
  for (int cb = 0; cb < 8; ++cb) acc[cb] = (f32x4){0.f, 0.f, 0.f, 0.f};
#pragma unroll
  for (int k0 = 0; k0 < 4; ++k0)
#pragma unroll
    for (int cb = 0; cb < 8; ++cb) {
      bf16x8 bfr = *(const bf16x8*)(BT + (size_t)(cb * 16 + t) * 128 + k0 * 32 + g * 8);
      acc[cb] = __builtin_amdgcn_mfma_f32_16x16x32_bf16(af[k0], bfr, acc[cb], 0, 0, 0);
    }

  int rbase = lb * 64 + wv * 16 + g * 4;
#pragma unroll
  for (int cb = 0; cb < 8; ++cb)
#pragma unroll
    for (int j = 0; j < 4; ++j) {
      int lr = rbase + j;
      if (lr < n) uuHb[(size_t)(gbase + lr) * DD + cb * 16 + t] = f2bf(acc[cb][j]);
    }
}

// ---------------- L1: hist ∥ transp ----------------
__global__ __launch_bounds__(256)
void hist_transp(const int* __restrict__ rows, int* __restrict__ cnt, int E,
                 const float* __restrict__ uh, const float* __restrict__ ih,
                 u16* __restrict__ uhT, u16* __restrict__ ihT) {
  int b = blockIdx.x;
  if (b < NSC) {
    int e = b * 256 + threadIdx.x;
    if (e < E) atomicAdd(&cnt[rows[e]], 1);
    return;
  }
  const float* B = (b - NSC) ? ih : uh;
  u16* BT = (b - NSC) ? ihT : uhT;
  for (int i = threadIdx.x; i < 16384; i += 256) {
    int r = i >> 7, c = i & 127;
    BT[c * 128 + r] = f2bf(B[r * 128 + c]);
  }
}

// ---------------- L2/L3: multi-block scan ----------------
__global__ __launch_bounds__(256)
void scan1_k(const int* __restrict__ cnt, int* __restrict__ tmp, int* __restrict__ part) {
  __shared__ int s[256];
  int gid = blockIdx.x * 256 + threadIdx.x;
  s[threadIdx.x] = (gid < NT) ? cnt[gid] : 0;
  __syncthreads();
#pragma unroll
  for (int off = 1; off < 256; off <<= 1) {
    int add = (threadIdx.x >= off) ? s[threadIdx.x - off] : 0;
    __syncthreads();
    s[threadIdx.x] += add;
    __syncthreads();
  }
  if (gid < NT) tmp[gid] = s[threadIdx.x];
  if (threadIdx.x == 255) part[blockIdx.x] = s[255];
}

__global__ __launch_bounds__(512)
void scan2_k(int* __restrict__ part) {
  __shared__ int s[512];
  s[threadIdx.x] = (threadIdx.x < NCH) ? part[threadIdx.x] : 0;
  __syncthreads();
#pragma unroll
  for (int off = 1; off < 512; off <<= 1) {
    int add = (threadIdx.x >= off) ? s[threadIdx.x - off] : 0;
    __syncthreads();
    s[threadIdx.x] += add;
    __syncthreads();
  }
  if (threadIdx.x < NCH) part[threadIdx.x] = s[threadIdx.x];
}

// ---------------- L4: scan3 ∥ proj ∥ zero-lat ----------------
__global__ __launch_bounds__(256)
void scan3_proj_zero(const int* __restrict__ tmp, const int* __restrict__ part,
                     int* __restrict__ row_ptr,
                     const float* __restrict__ Au, const float* __restrict__ Ai,
                     const u16* __restrict__ BTu, const u16* __restrict__ BTi,
                     u16* __restrict__ uuHb, u16* __restrict__ e0bf,
                     float* __restrict__ latZ) {
  int b = blockIdx.x;
  if (b < NCH) {
    int gid = b * 256 + threadIdx.x;
    if (gid < NT) {
      int off = b ? part[b - 1] : 0;
      row_ptr[gid + 1] = tmp[gid] + off;
    }
    if (gid == 0) row_ptr[0] = 0;
    return;
  }
  if (b >= NCH + NBM) {
    int zb = b - NCH - NBM;
    int base = (zb * 256 + threadIdx.x) * 16;
    f32x4 z = {0.f, 0.f, 0.f, 0.f};
#pragma unroll
    for (int j = 0; j < 4; ++j) *(f32x4*)(latZ + base + j * 4) = z;
    return;
  }
  proj_body(b - NCH, threadIdx.x, Au, Ai, BTu, BTi, uuHb, e0bf);
}

// ---------------- L5: tn(layer0) ∥ scatter ----------------
__global__ __launch_bounds__(256)
void tn_scatter(const u16* __restrict__ Ab, const u16* __restrict__ e0bf,
                float* __restrict__ latU, float* __restrict__ latI,
                const int* __restrict__ rows, const int* __restrict__ cols,
                const float* __restrict__ vals, const int* __restrict__ row_ptr,
                int* __restrict__ cursor, int2* __restrict__ sedge, int E) {
  __shared__ u32 ATs[1024];
  __shared__ u32 BTs[1024];
  int b = blockIdx.x;
  if (b < NB_TN4) {
    tn_body(b, threadIdx.x, Ab, e0bf, latU, latI, ATs, BTs);
    return;
  }
  int e = (b - NB_TN4) * 256 + threadIdx.x;
  if (e >= E) return;
  int r = rows[e];
  int p = row_ptr[r] + atomicAdd(&cursor[r], 1);
  int2 ev; ev.x = cols[e]; ev.y = __float_as_int(vals[e]);
  sedge[p] = ev;
}

// ---------------- L6: vg1 ∥ spmm(layer0) ----------------
__global__ __launch_bounds__(256)
void vg1_spmm(const float* __restrict__ V, const float* __restrict__ inU,
              const float* __restrict__ inI, float* __restrict__ outU,
              float* __restrict__ outI,
              const int* __restrict__ rp, const int2* __restrict__ se,
              const u16* __restrict__ pb, float* __restrict__ G,
              u16* __restrict__ Gb) {
  int b = blockIdx.x;
  if (b < 32) {
    const float* in = b < 16 ? inU : inI;
    float* outp = b < 16 ? outU : outI;
    int row = (b & 15) * 8 + (threadIdx.x >> 5);
    int c4 = (threadIdx.x & 31) * 4;
    float4 acc = make_float4(0.f, 0.f, 0.f, 0.f);
    for (int k = 0; k < 128; ++k) {
      float v = V[row * 128 + k];
      float4 l = *(const float4*)(in + k * 128 + c4);
      l.x = lrelu(l.x); l.y = lrelu(l.y); l.z = lrelu(l.z); l.w = lrelu(l.w);
      acc.x = fmaf(v, l.x, acc.x);
      acc.y = fmaf(v, l.y, acc.y);
      acc.z = fmaf(v, l.z, acc.z);
      acc.w = fmaf(v, l.w, acc.w);
    }
    float4 r = *(const float4*)(in + row * 128 + c4);
    float4 o;
    o.x = lrelu(acc.x) + lrelu(r.x);
    o.y = lrelu(acc.y) + lrelu(r.y);
    o.z = lrelu(acc.z) + lrelu(r.z);
    o.w = lrelu(acc.w) + lrelu(r.w);
    *(float4*)(outp + row * 128 + c4) = o;
    return;
  }
  int r = (b - 32) * 4 + (threadIdx.x >> 6);
  spmm_body(r, threadIdx.x, rp, se, pb, G, Gb);
}

// plain vg1 (layer 1)
__global__ __launch_bounds__(256)
void vg1_k(const float* __restrict__ V, const float* __restrict__ inU,
           const float* __restrict__ inI, float* __restrict__ outU,
           float* __restrict__ outI) {
  const float* in = blockIdx.x < 16 ? inU : inI;
  float* outp = blockIdx.x < 16 ? outU : outI;
  int row = (blockIdx.x & 15) * 8 + (threadIdx.x >> 5);
  int c4 = (threadIdx.x & 31) * 4;
  float4 acc = make_float4(0.f, 0.f, 0.f, 0.f);
  for (int k = 0; k < 128; ++k) {
    float v = V[row * 128 + k];
    float4 l = *(const float4*)(in + k * 128 + c4);
    l.x = lrelu(l.x); l.y = lrelu(l.y); l.z = lrelu(l.z); l.w = lrelu(l.w);
    acc.x = fmaf(v, l.x, acc.x);
    acc.y = fmaf(v, l.y, acc.y);
    acc.z = fmaf(v, l.z, acc.z);
    acc.w = fmaf(v, l.w, acc.w);
  }
  float4 r = *(const float4*)(in + row * 128 + c4);
  float4 o;
  o.x = lrelu(acc.x) + lrelu(r.x);
  o.y = lrelu(acc.y) + lrelu(r.y);
  o.z = lrelu(acc.z) + lrelu(r.z);
  o.w = lrelu(acc.w) + lrelu(r.w);
  *(float4*)(outp + row * 128 + c4) = o;
}

// vg2 + zero-lat
__global__ __launch_bounds__(256)
void vg2_zero(const float* __restrict__ V, const float* __restrict__ inU,
              const float* __restrict__ inI, u16* __restrict__ outU,
              u16* __restrict__ outI, float* __restrict__ latZ) {
  if (blockIdx.x >= 32) {
    int zb = blockIdx.x - 32;
    int base = (zb * 256 + threadIdx.x) * 16;
    f32x4 z = {0.f, 0.f, 0.f, 0.f};
#pragma unroll
    for (int j = 0; j < 4; ++j) *(f32x4*)(latZ + base + j * 4) = z;
    return;
  }
  const float* in = blockIdx.x < 16 ? inU : inI;
  u16* BT = blockIdx.x < 16 ? outU : outI;
  int row = (blockIdx.x & 15) * 8 + (threadIdx.x >> 5);
  int c4 = (threadIdx.x & 31) * 4;
  float4 acc = make_float4(0.f, 0.f, 0.f, 0.f);
  for (int k = 0; k < 128; ++k) {
    float v = V[row * 128 + k];
    float4 l = *(const float4*)(in + k * 128 + c4);
    acc.x = fmaf(v, l.x, acc.x);
    acc.y = fmaf(v, l.y, acc.y);
    acc.z = fmaf(v, l.z, acc.z);
    acc.w = fmaf(v, l.w, acc.w);
  }
  float4 r = *(const float4*)(in + row * 128 + c4);
  BT[(size_t)(c4 + 0) * 128 + row] = f2bf(lrelu(acc.x) + r.x);
  BT[(size_t)(c4 + 1) * 128 + row] = f2bf(lrelu(acc.y) + r.y);
  BT[(size_t)(c4 + 2) * 128 + row] = f2bf(lrelu(acc.z) + r.z);
  BT[(size_t)(c4 + 3) * 128 + row] = f2bf(lrelu(acc.w) + r.w);
}

// layer-1 fused: tn ∥ spmm on prevb
__global__ __launch_bounds__(256)
void layer_fused(const int* __restrict__ rp, const int2* __restrict__ se,
                 const u16* __restrict__ pb, float* __restrict__ G,
                 u16* __restrict__ Gb, const u16* __restrict__ Ab,
                 float* __restrict__ latU, float* __restrict__ latI) {
  __shared__ u32 ATs[1024];
  __shared__ u32 BTs[1024];
  int b = blockIdx.x;
  if (b < NB_TN4) {
    tn_body(b, threadIdx.x, Ab, pb, latU, latI, ATs, BTs);
    return;
  }
  int r = (b - NB_TN4) * 4 + (threadIdx.x >> 6);
  spmm_body(r, threadIdx.x, rp, se, pb, G, Gb);
}

// hyper GEMM + fused epilogue. H/out are never re-read — nontemporal stores.
template<int LAYER>
__global__ __launch_bounds__(256)
void hyp_mfma(const u16* __restrict__ Ab,
              const u16* __restrict__ BTu, const u16* __restrict__ BTi,
              const u16* __restrict__ Gb, u16* __restrict__ prevb,
              const u16* __restrict__ e0bf,
              float* __restrict__ H, float* __restrict__ out) {
  int b = blockIdx.x;
  bool usr = b < NBU_M;
  const u16* BT = usr ? BTu : BTi;
  int n = usr ? NU : NI;
  int lb = usr ? b : b - NBU_M;
  int gbase = usr ? 0 : NU;

  int wv = threadIdx.x >> 6, lane = threadIdx.x & 63;
  int t = lane & 15, g = lane >> 4;
  int rowa = lb * 64 + wv * 16 + t;
  int ra = rowa < n ? rowa : (n - 1);
  const u16* ap = Ab + (size_t)(gbase + ra) * DD;

  bf16x8 af[4];
#pragma unroll
  for (int k0 = 0; k0 < 4; ++k0)
    af[k0] = *(const bf16x8*)(ap + k0 * 32 + g * 8);

  f32x4 acc[8];
#pragma unroll
  for (int cb = 0; cb < 8; ++cb) acc[cb] = (f32x4){0.f, 0.f, 0.f, 0.f};
#pragma unroll
  for (int k0 = 0; k0 < 4; ++k0)
#pragma unroll
    for (int cb = 0; cb < 8; ++cb) {
      bf16x8 bfr = *(const bf16x8*)(BT + (size_t)(cb * 16 + t) * 128 + k0 * 32 + g * 8);
      acc[cb] = __builtin_amdgcn_mfma_f32_16x16x32_bf16(af[k0], bfr, acc[cb], 0, 0, 0);
    }

  int rbase = lb * 64 + wv * 16 + g * 4;
#pragma unroll
  for (int cb = 0; cb < 8; ++cb)
#pragma unroll
    for (int j = 0; j < 4; ++j) {
      int lr = rbase + j;
      if (lr < n) {
        size_t gi = (size_t)(gbase + lr) * DD + cb * 16 + t;
        float h = lrelu(acc[cb][j]);
        float gv = bf1(Gb[gi]);
        __builtin_nontemporal_store(h, H + gi);
        if (LAYER == 0) {
          prevb[gi] = f2bf(gv + h);   // prevb IS the next gather table — keep cached
        } else {
          __builtin_nontemporal_store(
              bf1(e0bf[gi]) + bf1(prevb[gi]) + gv + h, out + gi);
        }
      }
    }
}

extern "C" void kernel_launch(void* const* d_in, const int* in_sizes, int n_in,
                              void* d_out, int out_size, void* d_ws, size_t ws_size,
                              hipStream_t stream) {
  const float* u_emb = (const float*)d_in[0];
  const float* i_emb = (const float*)d_in[1];
  const float* u_hyp = (const float*)d_in[2];
  const float* i_hyp = (const float*)d_in[3];
  const float* Vm    = (const float*)d_in[4];
  const int*   rows  = (const int*)d_in[5];
  const int*   cols  = (const int*)d_in[6];
  const float* vals  = (const float*)d_in[7];
  int E = in_sizes[5];

  float* out = (float*)d_out;
  float* OUT_G = out + (size_t)NT * DD;        // gnn_lats [2,N,D]
  float* OUT_H = out + (size_t)3 * NT * DD;    // hyper_lats [2,N,D]

  char* w = (char*)d_ws;
  u16* uuHb   = (u16*)w;              w += (size_t)NT * DD * 2;
  u16* e0bf   = (u16*)w;              w += (size_t)NT * DD * 2;
  u16* prevb  = (u16*)w;              w += (size_t)NT * DD * 2;
  u16* Gb     = (u16*)w;              w += (size_t)NT * DD * 2;
  float* latU = (float*)w;            w += 16384 * 4;
  float* latI = (float*)w;            w += 16384 * 4;   // contiguous with latU
  float* lat2U = (float*)w;           w += 16384 * 4;
  float* lat2I = (float*)w;           w += 16384 * 4;
  u16* uhT    = (u16*)w;              w += 16384 * 2;
  u16* ihT    = (u16*)w;              w += 16384 * 2;
  u16* latTu  = (u16*)w;              w += 16384 * 2;
  u16* latTi  = (u16*)w;              w += 16384 * 2;
  int* row_cnt = (int*)w;             w += (size_t)NT * 4;
  int* cursor  = (int*)w;             w += (size_t)NT * 4;  // contiguous with row_cnt
  int* row_ptr = (int*)w;             w += (size_t)(NT + 1) * 4;
  int* tmp     = (int*)w;             w += (size_t)NT * 4;
  int* part    = (int*)w;             w += 512 * 4;
  int2* sedge  = (int2*)w;            w += (size_t)EDG * 8;

  float* G0 = OUT_G;
  float* G1 = OUT_G + (size_t)NT * DD;
  float* H0 = OUT_H;
  float* H1 = OUT_H + (size_t)NT * DD;

  // L0: zero row_cnt + cursor
  hipMemsetAsync(row_cnt, 0, sizeof(int) * 2 * NT, stream);
  // L1: hist ∥ transp
  hist_transp<<<NSC + 2, 256, 0, stream>>>(rows, row_cnt, E, u_hyp, i_hyp, uhT, ihT);
  // L2: scan1 (multi-block)
  scan1_k<<<NCH, 256, 0, stream>>>(row_cnt, tmp, part);
  // L3: scan2
  scan2_k<<<1, 512, 0, stream>>>(part);
  // L4: scan3 ∥ proj ∥ zero-lat
  scan3_proj_zero<<<NCH + NBM + 8, 256, 0, stream>>>(
      tmp, part, row_ptr, u_emb, i_emb, uhT, ihT, uuHb, e0bf, latU);
  // L5: tn(layer0) ∥ scatter
  tn_scatter<<<NB_TN4 + NSC, 256, 0, stream>>>(
      uuHb, e0bf, latU, latI, rows, cols, vals, row_ptr, cursor, sedge, E);
  // L6: vg1 ∥ spmm(layer0)
  vg1_spmm<<<32 + NSPMM, 256, 0, stream>>>(
      Vm, latU, latI, lat2U, lat2I, row_ptr, sedge, e0bf, G0, Gb);
  // L7: vg2 ∥ zero-lat (for layer 1)
  vg2_zero<<<40, 256, 0, stream>>>(Vm, lat2U, lat2I, latTu, latTi, latU);
  // L8: hyp<0>  (H0, prevb)
  hyp_mfma<0><<<NBM, 256, 0, stream>>>(
      uuHb, latTu, latTi, Gb, prevb, e0bf, H0, out);
  // L9: layer-1 tn ∥ spmm on prevb
  layer_fused<<<NB_TN4 + NSPMM, 256, 0, stream>>>(
      row_ptr, sedge, prevb, G1, Gb, uuHb, latU, latI);
  // L10: vg1
  vg1_k<<<32, 256, 0, stream>>>(Vm, latU, latI, lat2U, lat2I);
  // L11: vg2 (zero part harmless)
  vg2_zero<<<40, 256, 0, stream>>>(Vm, lat2U, lat2I, latTu, latTi, latU);
  // L12: hyp<1>  (H1, out)
  hyp_mfma<1><<<NBM, 256, 0, stream>>>(
      uuHb, latTu, latTi, Gb, prevb, e0bf, H1, out);
}

// Round 16
// 457.092 us; speedup vs baseline: 1.5802x; 1.0639x over previous
//
#include <hip/hip_runtime.h>

#define NU 50000
#define NI 70000
#define NT 120000
#define DD 128
#define EDG 800000
#define NCH ((NT + 255) / 256)      // 469 scan chunks
#define CHK 512                     // tn row chunk (512: halves atomic epilogues)
#define NBU_TN ((NU + CHK - 1) / CHK)   // 98
#define NBI_TN ((NI + CHK - 1) / CHK)   // 137
#define NB_TN4 (4 * (NBU_TN + NBI_TN))  // 940 (64x64 quadrant blocks)
#define NBU_M ((NU + 63) / 64)      // 782
#define NBI_M ((NI + 63) / 64)      // 1094
#define NBM (NBU_M + NBI_M)         // 1876
#define NSC ((EDG + 255) / 256)     // 3125 scatter/hist blocks
#define NSPMM (NT / 4)              // 30000 spmm blocks
#define SLOPE 0.5f

typedef __attribute__((ext_vector_type(8))) short bf16x8;
typedef __attribute__((ext_vector_type(4))) float f32x4;
typedef unsigned short u16;
typedef unsigned int u32;

__device__ __forceinline__ float lrelu(float x) { return x >= 0.f ? x : SLOPE * x; }

__device__ __forceinline__ u16 f2bf(float x) {
  union { float f; u32 u; } t; t.f = x;
  u32 r = (t.u + 0x7fffu + ((t.u >> 16) & 1u)) >> 16;
  return (u16)r;
}
__device__ __forceinline__ float bflo(u32 u) {
  union { u32 u; float f; } t; t.u = u << 16; return t.f;
}
__device__ __forceinline__ float bfhi(u32 u) {
  union { u32 u; float f; } t; t.u = u & 0xffff0000u; return t.f;
}
__device__ __forceinline__ float bf1(u16 u) {
  union { u32 u; float f; } t; t.u = (u32)u << 16; return t.f;
}

// ---------------- shared device bodies ----------------

__device__ __forceinline__ void tn_body(int b, int tid,
                                        const u16* __restrict__ Ab,
                                        const u16* __restrict__ pb,
                                        float* __restrict__ latU,
                                        float* __restrict__ latI,
                                        u32* ATs, u32* BTs) {
  int quad = b & 3, cb = b >> 2;
  bool usr = cb < NBU_TN;
  int n = usr ? NU : NI;
  int gbase = usr ? 0 : NU;
  float* outp = usr ? latU : latI;
  int r0c = (usr ? cb : cb - NBU_TN) * CHK;
  int r1c = min(r0c + CHK, n);
  int hh = (quad >> 1) * 64, dh = (quad & 1) * 64;

  int rp2 = tid & 15;
  int sg = tid >> 4;
  int wv = tid >> 6, lane = tid & 63;
  int t = lane & 15, g = lane >> 4;
  int wr = wv >> 1, wc = wv & 1;

  f32x4 acc[2][2];
#pragma unroll
  for (int a = 0; a < 2; ++a)
#pragma unroll
    for (int c2 = 0; c2 < 2; ++c2) acc[a][c2] = (f32x4){0.f, 0.f, 0.f, 0.f};

  for (int r0 = r0c; r0 < r1c; r0 += 32) {
    int ra = r0 + 2 * rp2, rb2 = ra + 1;
    uint2 a0 = {0,0}, a1 = {0,0}, b0 = {0,0}, b1 = {0,0};
    if (ra < r1c) {
      a0 = *(const uint2*)(Ab + (size_t)(gbase + ra) * DD + hh + sg * 4);
      b0 = *(const uint2*)(pb + (size_t)(gbase + ra) * DD + dh + sg * 4);
    }
    if (rb2 < r1c) {
      a1 = *(const uint2*)(Ab + (size_t)(gbase + rb2) * DD + hh + sg * 4);
      b1 = *(const uint2*)(pb + (size_t)(gbase + rb2) * DD + dh + sg * 4);
    }
    __syncthreads();
#pragma unroll
    for (int j = 0; j < 4; ++j) {
      u32 alo = ((const u32*)&a0)[j >> 1], ahi = ((const u32*)&a1)[j >> 1];
      u32 blo = ((const u32*)&b0)[j >> 1], bhi = ((const u32*)&b1)[j >> 1];
      u32 wa, wb;
      if (j & 1) {
        wa = (alo >> 16) | (ahi & 0xffff0000u);
        wb = (blo >> 16) | (bhi & 0xffff0000u);
      } else {
        wa = (alo & 0xffffu) | (ahi << 16);
        wb = (blo & 0xffffu) | (bhi << 16);
      }
      int c = sg * 4 + j;
      int idx = c * 16 + (rp2 ^ ((c & 3) << 2));
      ATs[idx] = wa;
      BTs[idx] = wb;
    }
    __syncthreads();

    bf16x8 afr[2], bfr[2];
#pragma unroll
    for (int a = 0; a < 2; ++a) {
      int c = wr * 32 + a * 16 + t;
      afr[a] = *(const bf16x8*)&ATs[c * 16 + ((g ^ (c & 3)) << 2)];
    }
#pragma unroll
    for (int c2 = 0; c2 < 2; ++c2) {
      int c = wc * 32 + c2 * 16 + t;
      bfr[c2] = *(const bf16x8*)&BTs[c * 16 + ((g ^ (c & 3)) << 2)];
    }
#pragma unroll
    for (int a = 0; a < 2; ++a)
#pragma unroll
      for (int c2 = 0; c2 < 2; ++c2)
        acc[a][c2] = __builtin_amdgcn_mfma_f32_16x16x32_bf16(
            afr[a], bfr[c2], acc[a][c2], 0, 0, 0);
  }

#pragma unroll
  for (int a = 0; a < 2; ++a) {
    int h = hh + wr * 32 + a * 16 + g * 4;
#pragma unroll
    for (int c2 = 0; c2 < 2; ++c2) {
      int d = dh + wc * 32 + c2 * 16 + t;
#pragma unroll
      for (int j = 0; j < 4; ++j)
        atomicAdd(outp + (h + j) * 128 + d, acc[a][c2][j]);
    }
  }
}

__device__ __forceinline__ void spmm_body(int r, int tid,
                                          const int* __restrict__ rp,
                                          const int2* __restrict__ se,
                                          const u16* __restrict__ pb,
                                          float* __restrict__ G,
                                          u16* __restrict__ Gb) {
  int lane = tid & 63;
  int p0 = rp[r], p1 = rp[r + 1];
  int q = lane >> 4, l4 = lane & 15;
  float a0 = 0.f, a1 = 0.f, a2 = 0.f, a3 = 0.f;
  float a4 = 0.f, a5 = 0.f, a6 = 0.f, a7 = 0.f;
  int p = p0 + q;
  for (; p + 4 < p1; p += 8) {
    int2 e1 = se[p];
    int2 e2 = se[p + 4];
    uint4 u1 = *(const uint4*)(pb + (size_t)e1.x * DD + l4 * 8);
    uint4 u2 = *(const uint4*)(pb + (size_t)e2.x * DD + l4 * 8);
    float v1 = __int_as_float(e1.y), v2 = __int_as_float(e2.y);
    a0 = fmaf(v1, bflo(u1.x), a0); a1 = fmaf(v1, bfhi(u1.x), a1);
    a2 = fmaf(v1, bflo(u1.y), a2); a3 = fmaf(v1, bfhi(u1.y), a3);
    a4 = fmaf(v1, bflo(u1.z), a4); a5 = fmaf(v1, bfhi(u1.z), a5);
    a6 = fmaf(v1, bflo(u1.w), a6); a7 = fmaf(v1, bfhi(u1.w), a7);
    a0 = fmaf(v2, bflo(u2.x), a0); a1 = fmaf(v2, bfhi(u2.x), a1);
    a2 = fmaf(v2, bflo(u2.y), a2); a3 = fmaf(v2, bfhi(u2.y), a3);
    a4 = fmaf(v2, bflo(u2.z), a4); a5 = fmaf(v2, bfhi(u2.z), a5);
    a6 = fmaf(v2, bflo(u2.w), a6); a7 = fmaf(v2, bfhi(u2.w), a7);
  }
  if (p < p1) {
    int2 e1 = se[p];
    uint4 u1 = *(const uint4*)(pb + (size_t)e1.x * DD + l4 * 8);
    float v1 = __int_as_float(e1.y);
    a0 = fmaf(v1, bflo(u1.x), a0); a1 = fmaf(v1, bfhi(u1.x), a1);
    a2 = fmaf(v1, bflo(u1.y), a2); a3 = fmaf(v1, bfhi(u1.y), a3);
    a4 = fmaf(v1, bflo(u1.z), a4); a5 = fmaf(v1, bfhi(u1.z), a5);
    a6 = fmaf(v1, bflo(u1.w), a6); a7 = fmaf(v1, bfhi(u1.w), a7);
  }
  a0 += __shfl_xor(a0, 16, 64); a0 += __shfl_xor(a0, 32, 64);
  a1 += __shfl_xor(a1, 16, 64); a1 += __shfl_xor(a1, 32, 64);
  a2 += __shfl_xor(a2, 16, 64); a2 += __shfl_xor(a2, 32, 64);
  a3 += __shfl_xor(a3, 16, 64); a3 += __shfl_xor(a3, 32, 64);
  a4 += __shfl_xor(a4, 16, 64); a4 += __shfl_xor(a4, 32, 64);
  a5 += __shfl_xor(a5, 16, 64); a5 += __shfl_xor(a5, 32, 64);
  a6 += __shfl_xor(a6, 16, 64); a6 += __shfl_xor(a6, 32, 64);
  a7 += __shfl_xor(a7, 16, 64); a7 += __shfl_xor(a7, 32, 64);
  if (q == 0) {
    a0 = lrelu(a0); a1 = lrelu(a1); a2 = lrelu(a2); a3 = lrelu(a3);
    a4 = lrelu(a4); a5 = lrelu(a5); a6 = lrelu(a6); a7 = lrelu(a7);
    f32x4 o1 = {a0, a1, a2, a3};
    f32x4 o2 = {a4, a5, a6, a7};
    // G is never re-read (Gb sidecar used) — bypass caches.
    __builtin_nontemporal_store(o1, (f32x4*)(G + (size_t)r * DD + l4 * 8));
    __builtin_nontemporal_store(o2, (f32x4*)(G + (size_t)r * DD + l4 * 8 + 4));
    bf16x8 gb;
    gb[0] = (short)f2bf(a0); gb[1] = (short)f2bf(a1);
    gb[2] = (short)f2bf(a2); gb[3] = (short)f2bf(a3);
    gb[4] = (short)f2bf(a4); gb[5] = (short)f2bf(a5);
    gb[6] = (short)f2bf(a6); gb[7] = (short)f2bf(a7);
    *(bf16x8*)(Gb + (size_t)r * DD + l4 * 8) = gb;
  }
}

__device__ __forceinline__ void proj_body(int b, int tid,
                                          const float* __restrict__ Au,
                                          const float* __restrict__ Ai,
                                          const u16* __restrict__ BTu,
                                          const u16* __restrict__ BTi,
                                          u16* __restrict__ uuHb,
                                          u16* __restrict__ e0bf) {
  bool usr = b < NBU_M;
  const float* A = usr ? Au : Ai;
  const u16* BT = usr ? BTu : BTi;
  int n = usr ? NU : NI;
  int lb = usr ? b : b - NBU_M;
  int gbase = usr ? 0 : NU;

  int wv = tid >> 6, lane = tid & 63;
  int t = lane & 15, g = lane >> 4;
  int rowa = lb * 64 + wv * 16 + t;
  int ra = rowa < n ? rowa : (n - 1);
  const float* ap = A + (size_t)ra * DD;

  bf16x8 af[4];
#pragma unroll
  for (int k0 = 0; k0 < 4; ++k0) {
    // fp32 embeds are read exactly once — nontemporal to keep L2 for bf16 tables
    f32x4 x = __builtin_nontemporal_load((const f32x4*)(ap + k0 * 32 + g * 8));
    f32x4 y = __builtin_nontemporal_load((const f32x4*)(ap + k0 * 32 + g * 8 + 4));
    bf16x8 v;
    v[0] = (short)f2bf(x[0]); v[1] = (short)f2bf(x[1]);
    v[2] = (short)f2bf(x[2]); v[3] = (short)f2bf(x[3]);
    v[4] = (short)f2bf(y[0]); v[5] = (short)f2bf(y[1]);
    v[6] = (short)f2bf(y[2]); v[7] = (short)f2bf(y[3]);
    af[k0] = v;
  }
  if (rowa < n) {
#pragma unroll
    for (int k0 = 0; k0 < 4; ++k0)
      *(bf16x8*)(e0bf + (size_t)(gbase + rowa) * DD + k0 * 32 + g * 8) = af[k0];
  }

  f32x4 acc[8];
#pragma unroll
  for (int cb = 0; cb < 8; ++cb) acc[cb] = (f32x4){0.f, 0.f, 0.f, 0.f};
#pragma unroll
  for (int k0 = 0; k0 < 4; ++k0)
#pragma unroll
    for (int cb = 0; cb < 8; ++cb) {
      bf16x8 bfr = *(const bf16x8*)(BT + (size_t)(cb * 16 + t) * 128 + k0 * 32 + g * 8);
      acc[cb] = __builtin_amdgcn_mfma_f32_16x16x32_bf16(af[k0], bfr, acc[cb], 0, 0, 0);
    }

  int rbase = lb * 64 + wv * 16 + g * 4;
#pragma unroll
  for (int cb = 0; cb < 8; ++cb)
#pragma unroll
    for (int j = 0; j < 4; ++j) {
      int lr = rbase + j;
      if (lr < n) uuHb[(size_t)(gbase + lr) * DD + cb * 16 + t] = f2bf(acc[cb][j]);
    }
}

// ---------------- L1: hist ∥ transp ----------------
__global__ __launch_bounds__(256)
void hist_transp(const int* __restrict__ rows, int* __restrict__ cnt, int E,
                 const float* __restrict__ uh, const float* __restrict__ ih,
                 u16* __restrict__ uhT, u16* __restrict__ ihT) {
  int b = blockIdx.x;
  if (b < NSC) {
    int e = b * 256 + threadIdx.x;
    if (e < E) atomicAdd(&cnt[rows[e]], 1);
    return;
  }
  const float* B = (b - NSC) ? ih : uh;
  u16* BT = (b - NSC) ? ihT : uhT;
  for (int i = threadIdx.x; i < 16384; i += 256) {
    int r = i >> 7, c = i & 127;
    BT[c * 128 + r] = f2bf(B[r * 128 + c]);
  }
}

// ---------------- L2/L3: multi-block scan ----------------
__global__ __launch_bounds__(256)
void scan1_k(const int* __restrict__ cnt, int* __restrict__ tmp, int* __restrict__ part) {
  __shared__ int s[256];
  int gid = blockIdx.x * 256 + threadIdx.x;
  s[threadIdx.x] = (gid < NT) ? cnt[gid] : 0;
  __syncthreads();
#pragma unroll
  for (int off = 1; off < 256; off <<= 1) {
    int add = (threadIdx.x >= off) ? s[threadIdx.x - off] : 0;
    __syncthreads();
    s[threadIdx.x] += add;
    __syncthreads();
  }
  if (gid < NT) tmp[gid] = s[threadIdx.x];
  if (threadIdx.x == 255) part[blockIdx.x] = s[255];
}

__global__ __launch_bounds__(512)
void scan2_k(int* __restrict__ part) {
  __shared__ int s[512];
  s[threadIdx.x] = (threadIdx.x < NCH) ? part[threadIdx.x] : 0;
  __syncthreads();
#pragma unroll
  for (int off = 1; off < 512; off <<= 1) {
    int add = (threadIdx.x >= off) ? s[threadIdx.x - off] : 0;
    __syncthreads();
    s[threadIdx.x] += add;
    __syncthreads();
  }
  if (threadIdx.x < NCH) part[threadIdx.x] = s[threadIdx.x];
}

// ---------------- L4: scan3 ∥ proj ∥ zero-lat ----------------
__global__ __launch_bounds__(256)
void scan3_proj_zero(const int* __restrict__ tmp, const int* __restrict__ part,
                     int* __restrict__ row_ptr,
                     const float* __restrict__ Au, const float* __restrict__ Ai,
                     const u16* __restrict__ BTu, const u16* __restrict__ BTi,
                     u16* __restrict__ uuHb, u16* __restrict__ e0bf,
                     float* __restrict__ latZ) {
  int b = blockIdx.x;
  if (b < NCH) {
    int gid = b * 256 + threadIdx.x;
    if (gid < NT) {
      int off = b ? part[b - 1] : 0;
      row_ptr[gid + 1] = tmp[gid] + off;
    }
    if (gid == 0) row_ptr[0] = 0;
    return;
  }
  if (b >= NCH + NBM) {
    int zb = b - NCH - NBM;
    int base = (zb * 256 + threadIdx.x) * 16;
    f32x4 z = {0.f, 0.f, 0.f, 0.f};
#pragma unroll
    for (int j = 0; j < 4; ++j) *(f32x4*)(latZ + base + j * 4) = z;
    return;
  }
  proj_body(b - NCH, threadIdx.x, Au, Ai, BTu, BTi, uuHb, e0bf);
}

// ---------------- L5: tn(layer0) ∥ scatter ----------------
__global__ __launch_bounds__(256)
void tn_scatter(const u16* __restrict__ Ab, const u16* __restrict__ e0bf,
                float* __restrict__ latU, float* __restrict__ latI,
                const int* __restrict__ rows, const int* __restrict__ cols,
                const float* __restrict__ vals, const int* __restrict__ row_ptr,
                int* __restrict__ cursor, int2* __restrict__ sedge, int E) {
  __shared__ u32 ATs[1024];
  __shared__ u32 BTs[1024];
  int b = blockIdx.x;
  if (b < NB_TN4) {
    tn_body(b, threadIdx.x, Ab, e0bf, latU, latI, ATs, BTs);
    return;
  }
  int e = (b - NB_TN4) * 256 + threadIdx.x;
  if (e >= E) return;
  int r = rows[e];
  int p = row_ptr[r] + atomicAdd(&cursor[r], 1);
  int2 ev; ev.x = cols[e]; ev.y = __float_as_int(vals[e]);
  sedge[p] = ev;
}

// ---------------- L6: vg1 ∥ spmm(layer0) ----------------
__global__ __launch_bounds__(256)
void vg1_spmm(const float* __restrict__ V, const float* __restrict__ inU,
              const float* __restrict__ inI, float* __restrict__ outU,
              float* __restrict__ outI,
              const int* __restrict__ rp, const int2* __restrict__ se,
              const u16* __restrict__ pb, float* __restrict__ G,
              u16* __restrict__ Gb) {
  int b = blockIdx.x;
  if (b < 32) {
    const float* in = b < 16 ? inU : inI;
    float* outp = b < 16 ? outU : outI;
    int row = (b & 15) * 8 + (threadIdx.x >> 5);
    int c4 = (threadIdx.x & 31) * 4;
    float4 acc = make_float4(0.f, 0.f, 0.f, 0.f);
    for (int k = 0; k < 128; ++k) {
      float v = V[row * 128 + k];
      float4 l = *(const float4*)(in + k * 128 + c4);
      l.x = lrelu(l.x); l.y = lrelu(l.y); l.z = lrelu(l.z); l.w = lrelu(l.w);
      acc.x = fmaf(v, l.x, acc.x);
      acc.y = fmaf(v, l.y, acc.y);
      acc.z = fmaf(v, l.z, acc.z);
      acc.w = fmaf(v, l.w, acc.w);
    }
    float4 r = *(const float4*)(in + row * 128 + c4);
    float4 o;
    o.x = lrelu(acc.x) + lrelu(r.x);
    o.y = lrelu(acc.y) + lrelu(r.y);
    o.z = lrelu(acc.z) + lrelu(r.z);
    o.w = lrelu(acc.w) + lrelu(r.w);
    *(float4*)(outp + row * 128 + c4) = o;
    return;
  }
  int r = (b - 32) * 4 + (threadIdx.x >> 6);
  spmm_body(r, threadIdx.x, rp, se, pb, G, Gb);
}

// plain vg1 (layer 1)
__global__ __launch_bounds__(256)
void vg1_k(const float* __restrict__ V, const float* __restrict__ inU,
           const float* __restrict__ inI, float* __restrict__ outU,
           float* __restrict__ outI) {
  const float* in = blockIdx.x < 16 ? inU : inI;
  float* outp = blockIdx.x < 16 ? outU : outI;
  int row = (blockIdx.x & 15) * 8 + (threadIdx.x >> 5);
  int c4 = (threadIdx.x & 31) * 4;
  float4 acc = make_float4(0.f, 0.f, 0.f, 0.f);
  for (int k = 0; k < 128; ++k) {
    float v = V[row * 128 + k];
    float4 l = *(const float4*)(in + k * 128 + c4);
    l.x = lrelu(l.x); l.y = lrelu(l.y); l.z = lrelu(l.z); l.w = lrelu(l.w);
    acc.x = fmaf(v, l.x, acc.x);
    acc.y = fmaf(v, l.y, acc.y);
    acc.z = fmaf(v, l.z, acc.z);
    acc.w = fmaf(v, l.w, acc.w);
  }
  float4 r = *(const float4*)(in + row * 128 + c4);
  float4 o;
  o.x = lrelu(acc.x) + lrelu(r.x);
  o.y = lrelu(acc.y) + lrelu(r.y);
  o.z = lrelu(acc.z) + lrelu(r.z);
  o.w = lrelu(acc.w) + lrelu(r.w);
  *(float4*)(outp + row * 128 + c4) = o;
}

// vg2 + zero-lat
__global__ __launch_bounds__(256)
void vg2_zero(const float* __restrict__ V, const float* __restrict__ inU,
              const float* __restrict__ inI, u16* __restrict__ outU,
              u16* __restrict__ outI, float* __restrict__ latZ) {
  if (blockIdx.x >= 32) {
    int zb = blockIdx.x - 32;
    int base = (zb * 256 + threadIdx.x) * 16;
    f32x4 z = {0.f, 0.f, 0.f, 0.f};
#pragma unroll
    for (int j = 0; j < 4; ++j) *(f32x4*)(latZ + base + j * 4) = z;
    return;
  }
  const float* in = blockIdx.x < 16 ? inU : inI;
  u16* BT = blockIdx.x < 16 ? outU : outI;
  int row = (blockIdx.x & 15) * 8 + (threadIdx.x >> 5);
  int c4 = (threadIdx.x & 31) * 4;
  float4 acc = make_float4(0.f, 0.f, 0.f, 0.f);
  for (int k = 0; k < 128; ++k) {
    float v = V[row * 128 + k];
    float4 l = *(const float4*)(in + k * 128 + c4);
    acc.x = fmaf(v, l.x, acc.x);
    acc.y = fmaf(v, l.y, acc.y);
    acc.z = fmaf(v, l.z, acc.z);
    acc.w = fmaf(v, l.w, acc.w);
  }
  float4 r = *(const float4*)(in + row * 128 + c4);
  BT[(size_t)(c4 + 0) * 128 + row] = f2bf(lrelu(acc.x) + r.x);
  BT[(size_t)(c4 + 1) * 128 + row] = f2bf(lrelu(acc.y) + r.y);
  BT[(size_t)(c4 + 2) * 128 + row] = f2bf(lrelu(acc.z) + r.z);
  BT[(size_t)(c4 + 3) * 128 + row] = f2bf(lrelu(acc.w) + r.w);
}

// layer-1 fused: tn ∥ spmm on prevb
__global__ __launch_bounds__(256)
void layer_fused(const int* __restrict__ rp, const int2* __restrict__ se,
                 const u16* __restrict__ pb, float* __restrict__ G,
                 u16* __restrict__ Gb, const u16* __restrict__ Ab,
                 float* __restrict__ latU, float* __restrict__ latI) {
  __shared__ u32 ATs[1024];
  __shared__ u32 BTs[1024];
  int b = blockIdx.x;
  if (b < NB_TN4) {
    tn_body(b, threadIdx.x, Ab, pb, latU, latI, ATs, BTs);
    return;
  }
  int r = (b - NB_TN4) * 4 + (threadIdx.x >> 6);
  spmm_body(r, threadIdx.x, rp, se, pb, G, Gb);
}

// hyper GEMM + fused epilogue. H/out are never re-read — nontemporal stores.
template<int LAYER>
__global__ __launch_bounds__(256)
void hyp_mfma(const u16* __restrict__ Ab,
              const u16* __restrict__ BTu, const u16* __restrict__ BTi,
              const u16* __restrict__ Gb, u16* __restrict__ prevb,
              const u16* __restrict__ e0bf,
              float* __restrict__ H, float* __restrict__ out) {
  int b = blockIdx.x;
  bool usr = b < NBU_M;
  const u16* BT = usr ? BTu : BTi;
  int n = usr ? NU : NI;
  int lb = usr ? b : b - NBU_M;
  int gbase = usr ? 0 : NU;

  int wv = threadIdx.x >> 6, lane = threadIdx.x & 63;
  int t = lane & 15, g = lane >> 4;
  int rowa = lb * 64 + wv * 16 + t;
  int ra = rowa < n ? rowa : (n - 1);
  const u16* ap = Ab + (size_t)(gbase + ra) * DD;

  bf16x8 af[4];
#pragma unroll
  for (int k0 = 0; k0 < 4; ++k0)
    af[k0] = *(const bf16x8*)(ap + k0 * 32 + g * 8);

  f32x4 acc[8];
#pragma unroll
  for (int cb = 0; cb < 8; ++cb) acc[cb] = (f32x4){0.f, 0.f, 0.f, 0.f};
#pragma unroll
  for (int k0 = 0; k0 < 4; ++k0)
#pragma unroll
    for (int cb = 0; cb < 8; ++cb) {
      bf16x8 bfr = *(const bf16x8*)(BT + (size_t)(cb * 16 + t) * 128 + k0 * 32 + g * 8);
      acc[cb] = __builtin_amdgcn_mfma_f32_16x16x32_bf16(af[k0], bfr, acc[cb], 0, 0, 0);
    }

  int rbase = lb * 64 + wv * 16 + g * 4;
#pragma unroll
  for (int cb = 0; cb < 8; ++cb)
#pragma unroll
    for (int j = 0; j < 4; ++j) {
      int lr = rbase + j;
      if (lr < n) {
        size_t gi = (size_t)(gbase + lr) * DD + cb * 16 + t;
        float h = lrelu(acc[cb][j]);
        float gv = bf1(Gb[gi]);
        __builtin_nontemporal_store(h, H + gi);
        if (LAYER == 0) {
          prevb[gi] = f2bf(gv + h);   // prevb IS the next gather table — keep cached
        } else {
          __builtin_nontemporal_store(
              bf1(e0bf[gi]) + bf1(prevb[gi]) + gv + h, out + gi);
        }
      }
    }
}

extern "C" void kernel_launch(void* const* d_in, const int* in_sizes, int n_in,
                              void* d_out, int out_size, void* d_ws, size_t ws_size,
                              hipStream_t stream) {
  const float* u_emb = (const float*)d_in[0];
  const float* i_emb = (const float*)d_in[1];
  const float* u_hyp = (const float*)d_in[2];
  const float* i_hyp = (const float*)d_in[3];
  const float* Vm    = (const float*)d_in[4];
  const int*   rows  = (const int*)d_in[5];
  const int*   cols  = (const int*)d_in[6];
  const float* vals  = (const float*)d_in[7];
  int E = in_sizes[5];

  float* out = (float*)d_out;
  float* OUT_G = out + (size_t)NT * DD;        // gnn_lats [2,N,D]
  float* OUT_H = out + (size_t)3 * NT * DD;    // hyper_lats [2,N,D]

  char* w = (char*)d_ws;
  u16* uuHb   = (u16*)w;              w += (size_t)NT * DD * 2;
  u16* e0bf   = (u16*)w;              w += (size_t)NT * DD * 2;
  u16* prevb  = (u16*)w;              w += (size_t)NT * DD * 2;
  u16* Gb     = (u16*)w;              w += (size_t)NT * DD * 2;
  float* latU = (float*)w;            w += 16384 * 4;
  float* latI = (float*)w;            w += 16384 * 4;   // contiguous with latU
  float* lat2U = (float*)w;           w += 16384 * 4;
  float* lat2I = (float*)w;           w += 16384 * 4;
  u16* uhT    = (u16*)w;              w += 16384 * 2;
  u16* ihT    = (u16*)w;              w += 16384 * 2;
  u16* latTu  = (u16*)w;              w += 16384 * 2;
  u16* latTi  = (u16*)w;              w += 16384 * 2;
  int* row_cnt = (int*)w;             w += (size_t)NT * 4;
  int* cursor  = (int*)w;             w += (size_t)NT * 4;  // contiguous with row_cnt
  int* row_ptr = (int*)w;             w += (size_t)(NT + 1) * 4;
  int* tmp     = (int*)w;             w += (size_t)NT * 4;
  int* part    = (int*)w;             w += 512 * 4;
  int2* sedge  = (int2*)w;            w += (size_t)EDG * 8;

  float* G0 = OUT_G;
  float* G1 = OUT_G + (size_t)NT * DD;
  float* H0 = OUT_H;
  float* H1 = OUT_H + (size_t)NT * DD;

  // L0: zero row_cnt + cursor
  hipMemsetAsync(row_cnt, 0, sizeof(int) * 2 * NT, stream);
  // L1: hist ∥ transp
  hist_transp<<<NSC + 2, 256, 0, stream>>>(rows, row_cnt, E, u_hyp, i_hyp, uhT, ihT);
  // L2: scan1 (multi-block)
  scan1_k<<<NCH, 256, 0, stream>>>(row_cnt, tmp, part);
  // L3: scan2
  scan2_k<<<1, 512, 0, stream>>>(part);
  // L4: scan3 ∥ proj ∥ zero-lat
  scan3_proj_zero<<<NCH + NBM + 8, 256, 0, stream>>>(
      tmp, part, row_ptr, u_emb, i_emb, uhT, ihT, uuHb, e0bf, latU);
  // L5: tn(layer0) ∥ scatter
  tn_scatter<<<NB_TN4 + NSC, 256, 0, stream>>>(
      uuHb, e0bf, latU, latI, rows, cols, vals, row_ptr, cursor, sedge, E);
  // L6: vg1 ∥ spmm(layer0)
  vg1_spmm<<<32 + NSPMM, 256, 0, stream>>>(
      Vm, latU, latI, lat2U, lat2I, row_ptr, sedge, e0bf, G0, Gb);
  // L7: vg2 ∥ zero-lat (for layer 1)
  vg2_zero<<<40, 256, 0, stream>>>(Vm, lat2U, lat2I, latTu, latTi, latU);
  // L8: hyp<0>  (H0, prevb)
  hyp_mfma<0><<<NBM, 256, 0, stream>>>(
      uuHb, latTu, latTi, Gb, prevb, e0bf, H0, out);
  // L9: layer-1 tn ∥ spmm on prevb
  layer_fused<<<NB_TN4 + NSPMM, 256, 0, stream>>>(
      row_ptr, sedge, prevb, G1, Gb, uuHb, latU, latI);
  // L10: vg1
  vg1_k<<<32, 256, 0, stream>>>(Vm, latU, latI, lat2U, lat2I);
  // L11: vg2 (zero part harmless)
  vg2_zero<<<40, 256, 0, stream>>>(Vm, lat2U, lat2I, latTu, latTi, latU);
  // L12: hyp<1>  (H1, out)
  hyp_mfma<1><<<NBM, 256, 0, stream>>>(
      uuHb, latTu, latTi, Gb, prevb, e0bf, H1, out);
}

// Round 17
// 454.308 us; speedup vs baseline: 1.5899x; 1.0061x over previous
//
#include <hip/hip_runtime.h>

#define NU 50000
#define NI 70000
#define NT 120000
#define DD 128
#define EDG 800000
#define NCH ((NT + 255) / 256)      // 469 scan chunks
#define CHK 1024                    // tn row chunk (1024: quarters atomic epilogues vs 256)
#define NBU_TN ((NU + CHK - 1) / CHK)   // 49
#define NBI_TN ((NI + CHK - 1) / CHK)   // 69
#define NB_TN4 (4 * (NBU_TN + NBI_TN))  // 472 (64x64 quadrant blocks)
#define NBU_M ((NU + 63) / 64)      // 782
#define NBI_M ((NI + 63) / 64)      // 1094
#define NBM (NBU_M + NBI_M)         // 1876
#define NSC ((EDG + 255) / 256)     // 3125 scatter/hist blocks
#define NSPMM (NT / 4)              // 30000 spmm blocks
#define SLOPE 0.5f

typedef __attribute__((ext_vector_type(8))) short bf16x8;
typedef __attribute__((ext_vector_type(4))) float f32x4;
typedef unsigned short u16;
typedef unsigned int u32;

__device__ __forceinline__ float lrelu(float x) { return x >= 0.f ? x : SLOPE * x; }

__device__ __forceinline__ u16 f2bf(float x) {
  union { float f; u32 u; } t; t.f = x;
  u32 r = (t.u + 0x7fffu + ((t.u >> 16) & 1u)) >> 16;
  return (u16)r;
}
__device__ __forceinline__ float bflo(u32 u) {
  union { u32 u; float f; } t; t.u = u << 16; return t.f;
}
__device__ __forceinline__ float bfhi(u32 u) {
  union { u32 u; float f; } t; t.u = u & 0xffff0000u; return t.f;
}
__device__ __forceinline__ float bf1(u16 u) {
  union { u32 u; float f; } t; t.u = (u32)u << 16; return t.f;
}

// ---------------- shared device bodies ----------------

__device__ __forceinline__ void tn_body(int b, int tid,
                                        const u16* __restrict__ Ab,
                                        const u16* __restrict__ pb,
                                        float* __restrict__ latU,
                                        float* __restrict__ latI,
                                        u32* ATs, u32* BTs) {
  int quad = b & 3, cb = b >> 2;
  bool usr = cb < NBU_TN;
  int n = usr ? NU : NI;
  int gbase = usr ? 0 : NU;
  float* outp = usr ? latU : latI;
  int r0c = (usr ? cb : cb - NBU_TN) * CHK;
  int r1c = min(r0c + CHK, n);
  int hh = (quad >> 1) * 64, dh = (quad & 1) * 64;

  int rp2 = tid & 15;
  int sg = tid >> 4;
  int wv = tid >> 6, lane = tid & 63;
  int t = lane & 15, g = lane >> 4;
  int wr = wv >> 1, wc = wv & 1;

  f32x4 acc[2][2];
#pragma unroll
  for (int a = 0; a < 2; ++a)
#pragma unroll
    for (int c2 = 0; c2 < 2; ++c2) acc[a][c2] = (f32x4){0.f, 0.f, 0.f, 0.f};

  for (int r0 = r0c; r0 < r1c; r0 += 32) {
    int ra = r0 + 2 * rp2, rb2 = ra + 1;
    uint2 a0 = {0,0}, a1 = {0,0}, b0 = {0,0}, b1 = {0,0};
    if (ra < r1c) {
      a0 = *(const uint2*)(Ab + (size_t)(gbase + ra) * DD + hh + sg * 4);
      b0 = *(const uint2*)(pb + (size_t)(gbase + ra) * DD + dh + sg * 4);
    }
    if (rb2 < r1c) {
      a1 = *(const uint2*)(Ab + (size_t)(gbase + rb2) * DD + hh + sg * 4);
      b1 = *(const uint2*)(pb + (size_t)(gbase + rb2) * DD + dh + sg * 4);
    }
    __syncthreads();
#pragma unroll
    for (int j = 0; j < 4; ++j) {
      u32 alo = ((const u32*)&a0)[j >> 1], ahi = ((const u32*)&a1)[j >> 1];
      u32 blo = ((const u32*)&b0)[j >> 1], bhi = ((const u32*)&b1)[j >> 1];
      u32 wa, wb;
      if (j & 1) {
        wa = (alo >> 16) | (ahi & 0xffff0000u);
        wb = (blo >> 16) | (bhi & 0xffff0000u);
      } else {
        wa = (alo & 0xffffu) | (ahi << 16);
        wb = (blo & 0xffffu) | (bhi << 16);
      }
      int c = sg * 4 + j;
      int idx = c * 16 + (rp2 ^ ((c & 3) << 2));
      ATs[idx] = wa;
      BTs[idx] = wb;
    }
    __syncthreads();

    bf16x8 afr[2], bfr[2];
#pragma unroll
    for (int a = 0; a < 2; ++a) {
      int c = wr * 32 + a * 16 + t;
      afr[a] = *(const bf16x8*)&ATs[c * 16 + ((g ^ (c & 3)) << 2)];
    }
#pragma unroll
    for (int c2 = 0; c2 < 2; ++c2) {
      int c = wc * 32 + c2 * 16 + t;
      bfr[c2] = *(const bf16x8*)&BTs[c * 16 + ((g ^ (c & 3)) << 2)];
    }
#pragma unroll
    for (int a = 0; a < 2; ++a)
#pragma unroll
      for (int c2 = 0; c2 < 2; ++c2)
        acc[a][c2] = __builtin_amdgcn_mfma_f32_16x16x32_bf16(
            afr[a], bfr[c2], acc[a][c2], 0, 0, 0);
  }

#pragma unroll
  for (int a = 0; a < 2; ++a) {
    int h = hh + wr * 32 + a * 16 + g * 4;
#pragma unroll
    for (int c2 = 0; c2 < 2; ++c2) {
      int d = dh + wc * 32 + c2 * 16 + t;
#pragma unroll
      for (int j = 0; j < 4; ++j)
        atomicAdd(outp + (h + j) * 128 + d, acc[a][c2][j]);
    }
  }
}

__device__ __forceinline__ void spmm_body(int r, int tid,
                                          const int* __restrict__ rp,
                                          const int2* __restrict__ se,
                                          const u16* __restrict__ pb,
                                          float* __restrict__ G,
                                          u16* __restrict__ Gb) {
  int lane = tid & 63;
  int p0 = rp[r], p1 = rp[r + 1];
  int q = lane >> 4, l4 = lane & 15;
  float a0 = 0.f, a1 = 0.f, a2 = 0.f, a3 = 0.f;
  float a4 = 0.f, a5 = 0.f, a6 = 0.f, a7 = 0.f;
  int p = p0 + q;
  for (; p + 4 < p1; p += 8) {
    int2 e1 = se[p];
    int2 e2 = se[p + 4];
    uint4 u1 = *(const uint4*)(pb + (size_t)e1.x * DD + l4 * 8);
    uint4 u2 = *(const uint4*)(pb + (size_t)e2.x * DD + l4 * 8);
    float v1 = __int_as_float(e1.y), v2 = __int_as_float(e2.y);
    a0 = fmaf(v1, bflo(u1.x), a0); a1 = fmaf(v1, bfhi(u1.x), a1);
    a2 = fmaf(v1, bflo(u1.y), a2); a3 = fmaf(v1, bfhi(u1.y), a3);
    a4 = fmaf(v1, bflo(u1.z), a4); a5 = fmaf(v1, bfhi(u1.z), a5);
    a6 = fmaf(v1, bflo(u1.w), a6); a7 = fmaf(v1, bfhi(u1.w), a7);
    a0 = fmaf(v2, bflo(u2.x), a0); a1 = fmaf(v2, bfhi(u2.x), a1);
    a2 = fmaf(v2, bflo(u2.y), a2); a3 = fmaf(v2, bfhi(u2.y), a3);
    a4 = fmaf(v2, bflo(u2.z), a4); a5 = fmaf(v2, bfhi(u2.z), a5);
    a6 = fmaf(v2, bflo(u2.w), a6); a7 = fmaf(v2, bfhi(u2.w), a7);
  }
  if (p < p1) {
    int2 e1 = se[p];
    uint4 u1 = *(const uint4*)(pb + (size_t)e1.x * DD + l4 * 8);
    float v1 = __int_as_float(e1.y);
    a0 = fmaf(v1, bflo(u1.x), a0); a1 = fmaf(v1, bfhi(u1.x), a1);
    a2 = fmaf(v1, bflo(u1.y), a2); a3 = fmaf(v1, bfhi(u1.y), a3);
    a4 = fmaf(v1, bflo(u1.z), a4); a5 = fmaf(v1, bfhi(u1.z), a5);
    a6 = fmaf(v1, bflo(u1.w), a6); a7 = fmaf(v1, bfhi(u1.w), a7);
  }
  a0 += __shfl_xor(a0, 16, 64); a0 += __shfl_xor(a0, 32, 64);
  a1 += __shfl_xor(a1, 16, 64); a1 += __shfl_xor(a1, 32, 64);
  a2 += __shfl_xor(a2, 16, 64); a2 += __shfl_xor(a2, 32, 64);
  a3 += __shfl_xor(a3, 16, 64); a3 += __shfl_xor(a3, 32, 64);
  a4 += __shfl_xor(a4, 16, 64); a4 += __shfl_xor(a4, 32, 64);
  a5 += __shfl_xor(a5, 16, 64); a5 += __shfl_xor(a5, 32, 64);
  a6 += __shfl_xor(a6, 16, 64); a6 += __shfl_xor(a6, 32, 64);
  a7 += __shfl_xor(a7, 16, 64); a7 += __shfl_xor(a7, 32, 64);
  if (q == 0) {
    a0 = lrelu(a0); a1 = lrelu(a1); a2 = lrelu(a2); a3 = lrelu(a3);
    a4 = lrelu(a4); a5 = lrelu(a5); a6 = lrelu(a6); a7 = lrelu(a7);
    f32x4 o1 = {a0, a1, a2, a3};
    f32x4 o2 = {a4, a5, a6, a7};
    // G is never re-read (Gb sidecar used) — bypass caches.
    __builtin_nontemporal_store(o1, (f32x4*)(G + (size_t)r * DD + l4 * 8));
    __builtin_nontemporal_store(o2, (f32x4*)(G + (size_t)r * DD + l4 * 8 + 4));
    bf16x8 gb;
    gb[0] = (short)f2bf(a0); gb[1] = (short)f2bf(a1);
    gb[2] = (short)f2bf(a2); gb[3] = (short)f2bf(a3);
    gb[4] = (short)f2bf(a4); gb[5] = (short)f2bf(a5);
    gb[6] = (short)f2bf(a6); gb[7] = (short)f2bf(a7);
    *(bf16x8*)(Gb + (size_t)r * DD + l4 * 8) = gb;
  }
}

__device__ __forceinline__ void proj_body(int b, int tid,
                                          const float* __restrict__ Au,
                                          const float* __restrict__ Ai,
                                          const u16* __restrict__ BTu,
                                          const u16* __restrict__ BTi,
                                          u16* __restrict__ uuHb,
                                          u16* __restrict__ e0bf) {
  bool usr = b < NBU_M;
  const float* A = usr ? Au : Ai;
  const u16* BT = usr ? BTu : BTi;
  int n = usr ? NU : NI;
  int lb = usr ? b : b - NBU_M;
  int gbase = usr ? 0 : NU;

  int wv = tid >> 6, lane = tid & 63;
  int t = lane & 15, g = lane >> 4;
  int rowa = lb * 64 + wv * 16 + t;
  int ra = rowa < n ? rowa : (n - 1);
  const float* ap = A + (size_t)ra * DD;

  bf16x8 af[4];
#pragma unroll
  for (int k0 = 0; k0 < 4; ++k0) {
    // fp32 embeds are read exactly once — nontemporal to keep L2 for bf16 tables
    f32x4 x = __builtin_nontemporal_load((const f32x4*)(ap + k0 * 32 + g * 8));
    f32x4 y = __builtin_nontemporal_load((const f32x4*)(ap + k0 * 32 + g * 8 + 4));
    bf16x8 v;
    v[0] = (short)f2bf(x[0]); v[1] = (short)f2bf(x[1]);
    v[2] = (short)f2bf(x[2]); v[3] = (short)f2bf(x[3]);
    v[4] = (short)f2bf(y[0]); v[5] = (short)f2bf(y[1]);
    v[6] = (short)f2bf(y[2]); v[7] = (short)f2bf(y[3]);
    af[k0] = v;
  }
  if (rowa < n) {
#pragma unroll
    for (int k0 = 0; k0 < 4; ++k0)
      *(bf16x8*)(e0bf + (size_t)(gbase + rowa) * DD + k0 * 32 + g * 8) = af[k0];
  }

  f32x4 acc[8];
#pragma unroll
  for (int cb = 0; cb < 8; ++cb) acc[cb] = (f32x4){0.f, 0.f, 0.f, 0.f};
#pragma unroll
  for (int k0 = 0; k0 < 4; ++k0)
#pragma unroll
    for (int cb = 0; cb < 8; ++cb) {
      bf16x8 bfr = *(const bf16x8*)(BT + (size_t)(cb * 16 + t) * 128 + k0 * 32 + g * 8);
      acc[cb] = __builtin_amdgcn_mfma_f32_16x16x32_bf16(af[k0], bfr, acc[cb], 0, 0, 0);
    }

  int rbase = lb * 64 + wv * 16 + g * 4;
#pragma unroll
  for (int cb = 0; cb < 8; ++cb)
#pragma unroll
    for (int j = 0; j < 4; ++j) {
      int lr = rbase + j;
      if (lr < n) uuHb[(size_t)(gbase + lr) * DD + cb * 16 + t] = f2bf(acc[cb][j]);
    }
}

// ---------------- L1: hist ∥ transp ----------------
__global__ __launch_bounds__(256)
void hist_transp(const int* __restrict__ rows, int* __restrict__ cnt, int E,
                 const float* __restrict__ uh, const float* __restrict__ ih,
                 u16* __restrict__ uhT, u16* __restrict__ ihT) {
  int b = blockIdx.x;
  if (b < NSC) {
    int e = b * 256 + threadIdx.x;
    if (e < E) atomicAdd(&cnt[rows[e]], 1);
    return;
  }
  const float* B = (b - NSC) ? ih : uh;
  u16* BT = (b - NSC) ? ihT : uhT;
  for (int i = threadIdx.x; i < 16384; i += 256) {
    int r = i >> 7, c = i & 127;
    BT[c * 128 + r] = f2bf(B[r * 128 + c]);
  }
}

// ---------------- L2/L3: multi-block scan ----------------
__global__ __launch_bounds__(256)
void scan1_k(const int* __restrict__ cnt, int* __restrict__ tmp, int* __restrict__ part) {
  __shared__ int s[256];
  int gid = blockIdx.x * 256 + threadIdx.x;
  s[threadIdx.x] = (gid < NT) ? cnt[gid] : 0;
  __syncthreads();
#pragma unroll
  for (int off = 1; off < 256; off <<= 1) {
    int add = (threadIdx.x >= off) ? s[threadIdx.x - off] : 0;
    __syncthreads();
    s[threadIdx.x] += add;
    __syncthreads();
  }
  if (gid < NT) tmp[gid] = s[threadIdx.x];
  if (threadIdx.x == 255) part[blockIdx.x] = s[255];
}

__global__ __launch_bounds__(512)
void scan2_k(int* __restrict__ part) {
  __shared__ int s[512];
  s[threadIdx.x] = (threadIdx.x < NCH) ? part[threadIdx.x] : 0;
  __syncthreads();
#pragma unroll
  for (int off = 1; off < 512; off <<= 1) {
    int add = (threadIdx.x >= off) ? s[threadIdx.x - off] : 0;
    __syncthreads();
    s[threadIdx.x] += add;
    __syncthreads();
  }
  if (threadIdx.x < NCH) part[threadIdx.x] = s[threadIdx.x];
}

// ---------------- L4: scan3 ∥ proj ∥ zero-lat ----------------
__global__ __launch_bounds__(256)
void scan3_proj_zero(const int* __restrict__ tmp, const int* __restrict__ part,
                     int* __restrict__ row_ptr,
                     const float* __restrict__ Au, const float* __restrict__ Ai,
                     const u16* __restrict__ BTu, const u16* __restrict__ BTi,
                     u16* __restrict__ uuHb, u16* __restrict__ e0bf,
                     float* __restrict__ latZ) {
  int b = blockIdx.x;
  if (b < NCH) {
    int gid = b * 256 + threadIdx.x;
    if (gid < NT) {
      int off = b ? part[b - 1] : 0;
      row_ptr[gid + 1] = tmp[gid] + off;
    }
    if (gid == 0) row_ptr[0] = 0;
    return;
  }
  if (b >= NCH + NBM) {
    int zb = b - NCH - NBM;
    int base = (zb * 256 + threadIdx.x) * 16;
    f32x4 z = {0.f, 0.f, 0.f, 0.f};
#pragma unroll
    for (int j = 0; j < 4; ++j) *(f32x4*)(latZ + base + j * 4) = z;
    return;
  }
  proj_body(b - NCH, threadIdx.x, Au, Ai, BTu, BTi, uuHb, e0bf);
}

// ---------------- L5: tn(layer0) ∥ scatter ----------------
__global__ __launch_bounds__(256)
void tn_scatter(const u16* __restrict__ Ab, const u16* __restrict__ e0bf,
                float* __restrict__ latU, float* __restrict__ latI,
                const int* __restrict__ rows, const int* __restrict__ cols,
                const float* __restrict__ vals, const int* __restrict__ row_ptr,
                int* __restrict__ cursor, int2* __restrict__ sedge, int E) {
  __shared__ u32 ATs[1024];
  __shared__ u32 BTs[1024];
  int b = blockIdx.x;
  if (b < NB_TN4) {
    tn_body(b, threadIdx.x, Ab, e0bf, latU, latI, ATs, BTs);
    return;
  }
  int e = (b - NB_TN4) * 256 + threadIdx.x;
  if (e >= E) return;
  int r = rows[e];
  int p = row_ptr[r] + atomicAdd(&cursor[r], 1);
  int2 ev; ev.x = cols[e]; ev.y = __float_as_int(vals[e]);
  sedge[p] = ev;
}

// ---------------- L6: vg1 ∥ spmm(layer0) ----------------
__global__ __launch_bounds__(256)
void vg1_spmm(const float* __restrict__ V, const float* __restrict__ inU,
              const float* __restrict__ inI, float* __restrict__ outU,
              float* __restrict__ outI,
              const int* __restrict__ rp, const int2* __restrict__ se,
              const u16* __restrict__ pb, float* __restrict__ G,
              u16* __restrict__ Gb) {
  int b = blockIdx.x;
  if (b < 32) {
    const float* in = b < 16 ? inU : inI;
    float* outp = b < 16 ? outU : outI;
    int row = (b & 15) * 8 + (threadIdx.x >> 5);
    int c4 = (threadIdx.x & 31) * 4;
    float4 acc = make_float4(0.f, 0.f, 0.f, 0.f);
    for (int k = 0; k < 128; ++k) {
      float v = V[row * 128 + k];
      float4 l = *(const float4*)(in + k * 128 + c4);
      l.x = lrelu(l.x); l.y = lrelu(l.y); l.z = lrelu(l.z); l.w = lrelu(l.w);
      acc.x = fmaf(v, l.x, acc.x);
      acc.y = fmaf(v, l.y, acc.y);
      acc.z = fmaf(v, l.z, acc.z);
      acc.w = fmaf(v, l.w, acc.w);
    }
    float4 r = *(const float4*)(in + row * 128 + c4);
    float4 o;
    o.x = lrelu(acc.x) + lrelu(r.x);
    o.y = lrelu(acc.y) + lrelu(r.y);
    o.z = lrelu(acc.z) + lrelu(r.z);
    o.w = lrelu(acc.w) + lrelu(r.w);
    *(float4*)(outp + row * 128 + c4) = o;
    return;
  }
  int r = (b - 32) * 4 + (threadIdx.x >> 6);
  spmm_body(r, threadIdx.x, rp, se, pb, G, Gb);
}

// plain vg1 (layer 1)
__global__ __launch_bounds__(256)
void vg1_k(const float* __restrict__ V, const float* __restrict__ inU,
           const float* __restrict__ inI, float* __restrict__ outU,
           float* __restrict__ outI) {
  const float* in = blockIdx.x < 16 ? inU : inI;
  float* outp = blockIdx.x < 16 ? outU : outI;
  int row = (blockIdx.x & 15) * 8 + (threadIdx.x >> 5);
  int c4 = (threadIdx.x & 31) * 4;
  float4 acc = make_float4(0.f, 0.f, 0.f, 0.f);
  for (int k = 0; k < 128; ++k) {
    float v = V[row * 128 + k];
    float4 l = *(const float4*)(in + k * 128 + c4);
    l.x = lrelu(l.x); l.y = lrelu(l.y); l.z = lrelu(l.z); l.w = lrelu(l.w);
    acc.x = fmaf(v, l.x, acc.x);
    acc.y = fmaf(v, l.y, acc.y);
    acc.z = fmaf(v, l.z, acc.z);
    acc.w = fmaf(v, l.w, acc.w);
  }
  float4 r = *(const float4*)(in + row * 128 + c4);
  float4 o;
  o.x = lrelu(acc.x) + lrelu(r.x);
  o.y = lrelu(acc.y) + lrelu(r.y);
  o.z = lrelu(acc.z) + lrelu(r.z);
  o.w = lrelu(acc.w) + lrelu(r.w);
  *(float4*)(outp + row * 128 + c4) = o;
}

// vg2 + zero-lat
__global__ __launch_bounds__(256)
void vg2_zero(const float* __restrict__ V, const float* __restrict__ inU,
              const float* __restrict__ inI, u16* __restrict__ outU,
              u16* __restrict__ outI, float* __restrict__ latZ) {
  if (blockIdx.x >= 32) {
    int zb = blockIdx.x - 32;
    int base = (zb * 256 + threadIdx.x) * 16;
    f32x4 z = {0.f, 0.f, 0.f, 0.f};
#pragma unroll
    for (int j = 0; j < 4; ++j) *(f32x4*)(latZ + base + j * 4) = z;
    return;
  }
  const float* in = blockIdx.x < 16 ? inU : inI;
  u16* BT = blockIdx.x < 16 ? outU : outI;
  int row = (blockIdx.x & 15) * 8 + (threadIdx.x >> 5);
  int c4 = (threadIdx.x & 31) * 4;
  float4 acc = make_float4(0.f, 0.f, 0.f, 0.f);
  for (int k = 0; k < 128; ++k) {
    float v = V[row * 128 + k];
    float4 l = *(const float4*)(in + k * 128 + c4);
    acc.x = fmaf(v, l.x, acc.x);
    acc.y = fmaf(v, l.y, acc.y);
    acc.z = fmaf(v, l.z, acc.z);
    acc.w = fmaf(v, l.w, acc.w);
  }
  float4 r = *(const float4*)(in + row * 128 + c4);
  BT[(size_t)(c4 + 0) * 128 + row] = f2bf(lrelu(acc.x) + r.x);
  BT[(size_t)(c4 + 1) * 128 + row] = f2bf(lrelu(acc.y) + r.y);
  BT[(size_t)(c4 + 2) * 128 + row] = f2bf(lrelu(acc.z) + r.z);
  BT[(size_t)(c4 + 3) * 128 + row] = f2bf(lrelu(acc.w) + r.w);
}

// layer-1 fused: tn ∥ spmm on prevb
__global__ __launch_bounds__(256)
void layer_fused(const int* __restrict__ rp, const int2* __restrict__ se,
                 const u16* __restrict__ pb, float* __restrict__ G,
                 u16* __restrict__ Gb, const u16* __restrict__ Ab,
                 float* __restrict__ latU, float* __restrict__ latI) {
  __shared__ u32 ATs[1024];
  __shared__ u32 BTs[1024];
  int b = blockIdx.x;
  if (b < NB_TN4) {
    tn_body(b, threadIdx.x, Ab, pb, latU, latI, ATs, BTs);
    return;
  }
  int r = (b - NB_TN4) * 4 + (threadIdx.x >> 6);
  spmm_body(r, threadIdx.x, rp, se, pb, G, Gb);
}

// hyper GEMM + fused epilogue. H/out are never re-read — nontemporal stores.
template<int LAYER>
__global__ __launch_bounds__(256)
void hyp_mfma(const u16* __restrict__ Ab,
              const u16* __restrict__ BTu, const u16* __restrict__ BTi,
              const u16* __restrict__ Gb, u16* __restrict__ prevb,
              const u16* __restrict__ e0bf,
              float* __restrict__ H, float* __restrict__ out) {
  int b = blockIdx.x;
  bool usr = b < NBU_M;
  const u16* BT = usr ? BTu : BTi;
  int n = usr ? NU : NI;
  int lb = usr ? b : b - NBU_M;
  int gbase = usr ? 0 : NU;

  int wv = threadIdx.x >> 6, lane = threadIdx.x & 63;
  int t = lane & 15, g = lane >> 4;
  int rowa = lb * 64 + wv * 16 + t;
  int ra = rowa < n ? rowa : (n - 1);
  const u16* ap = Ab + (size_t)(gbase + ra) * DD;

  bf16x8 af[4];
#pragma unroll
  for (int k0 = 0; k0 < 4; ++k0)
    af[k0] = *(const bf16x8*)(ap + k0 * 32 + g * 8);

  f32x4 acc[8];
#pragma unroll
  for (int cb = 0; cb < 8; ++cb) acc[cb] = (f32x4){0.f, 0.f, 0.f, 0.f};
#pragma unroll
  for (int k0 = 0; k0 < 4; ++k0)
#pragma unroll
    for (int cb = 0; cb < 8; ++cb) {
      bf16x8 bfr = *(const bf16x8*)(BT + (size_t)(cb * 16 + t) * 128 + k0 * 32 + g * 8);
      acc[cb] = __builtin_amdgcn_mfma_f32_16x16x32_bf16(af[k0], bfr, acc[cb], 0, 0, 0);
    }

  int rbase = lb * 64 + wv * 16 + g * 4;
#pragma unroll
  for (int cb = 0; cb < 8; ++cb)
#pragma unroll
    for (int j = 0; j < 4; ++j) {
      int lr = rbase + j;
      if (lr < n) {
        size_t gi = (size_t)(gbase + lr) * DD + cb * 16 + t;
        float h = lrelu(acc[cb][j]);
        float gv = bf1(Gb[gi]);
        __builtin_nontemporal_store(h, H + gi);
        if (LAYER == 0) {
          prevb[gi] = f2bf(gv + h);   // prevb IS the next gather table — keep cached
        } else {
          __builtin_nontemporal_store(
              bf1(e0bf[gi]) + bf1(prevb[gi]) + gv + h, out + gi);
        }
      }
    }
}

extern "C" void kernel_launch(void* const* d_in, const int* in_sizes, int n_in,
                              void* d_out, int out_size, void* d_ws, size_t ws_size,
                              hipStream_t stream) {
  const float* u_emb = (const float*)d_in[0];
  const float* i_emb = (const float*)d_in[1];
  const float* u_hyp = (const float*)d_in[2];
  const float* i_hyp = (const float*)d_in[3];
  const float* Vm    = (const float*)d_in[4];
  const int*   rows  = (const int*)d_in[5];
  const int*   cols  = (const int*)d_in[6];
  const float* vals  = (const float*)d_in[7];
  int E = in_sizes[5];

  float* out = (float*)d_out;
  float* OUT_G = out + (size_t)NT * DD;        // gnn_lats [2,N,D]
  float* OUT_H = out + (size_t)3 * NT * DD;    // hyper_lats [2,N,D]

  char* w = (char*)d_ws;
  u16* uuHb   = (u16*)w;              w += (size_t)NT * DD * 2;
  u16* e0bf   = (u16*)w;              w += (size_t)NT * DD * 2;
  u16* prevb  = (u16*)w;              w += (size_t)NT * DD * 2;
  u16* Gb     = (u16*)w;              w += (size_t)NT * DD * 2;
  float* latU = (float*)w;            w += 16384 * 4;
  float* latI = (float*)w;            w += 16384 * 4;   // contiguous with latU
  float* lat2U = (float*)w;           w += 16384 * 4;
  float* lat2I = (float*)w;           w += 16384 * 4;
  u16* uhT    = (u16*)w;              w += 16384 * 2;
  u16* ihT    = (u16*)w;              w += 16384 * 2;
  u16* latTu  = (u16*)w;              w += 16384 * 2;
  u16* latTi  = (u16*)w;              w += 16384 * 2;
  int* row_cnt = (int*)w;             w += (size_t)NT * 4;
  int* cursor  = (int*)w;             w += (size_t)NT * 4;  // contiguous with row_cnt
  int* row_ptr = (int*)w;             w += (size_t)(NT + 1) * 4;
  int* tmp     = (int*)w;             w += (size_t)NT * 4;
  int* part    = (int*)w;             w += 512 * 4;
  int2* sedge  = (int2*)w;            w += (size_t)EDG * 8;

  float* G0 = OUT_G;
  float* G1 = OUT_G + (size_t)NT * DD;
  float* H0 = OUT_H;
  float* H1 = OUT_H + (size_t)NT * DD;

  // L0: zero row_cnt + cursor
  hipMemsetAsync(row_cnt, 0, sizeof(int) * 2 * NT, stream);
  // L1: hist ∥ transp
  hist_transp<<<NSC + 2, 256, 0, stream>>>(rows, row_cnt, E, u_hyp, i_hyp, uhT, ihT);
  // L2: scan1 (multi-block)
  scan1_k<<<NCH, 256, 0, stream>>>(row_cnt, tmp, part);
  // L3: scan2
  scan2_k<<<1, 512, 0, stream>>>(part);
  // L4: scan3 ∥ proj ∥ zero-lat
  scan3_proj_zero<<<NCH + NBM + 8, 256, 0, stream>>>(
      tmp, part, row_ptr, u_emb, i_emb, uhT, ihT, uuHb, e0bf, latU);
  // L5: tn(layer0) ∥ scatter
  tn_scatter<<<NB_TN4 + NSC, 256, 0, stream>>>(
      uuHb, e0bf, latU, latI, rows, cols, vals, row_ptr, cursor, sedge, E);
  // L6: vg1 ∥ spmm(layer0)
  vg1_spmm<<<32 + NSPMM, 256, 0, stream>>>(
      Vm, latU, latI, lat2U, lat2I, row_ptr, sedge, e0bf, G0, Gb);
  // L7: vg2 ∥ zero-lat (for layer 1)
  vg2_zero<<<40, 256, 0, stream>>>(Vm, lat2U, lat2I, latTu, latTi, latU);
  // L8: hyp<0>  (H0, prevb)
  hyp_mfma<0><<<NBM, 256, 0, stream>>>(
      uuHb, latTu, latTi, Gb, prevb, e0bf, H0, out);
  // L9: layer-1 tn ∥ spmm on prevb
  layer_fused<<<NB_TN4 + NSPMM, 256, 0, stream>>>(
      row_ptr, sedge, prevb, G1, Gb, uuHb, latU, latI);
  // L10: vg1
  vg1_k<<<32, 256, 0, stream>>>(Vm, latU, latI, lat2U, lat2I);
  // L11: vg2 (zero part harmless)
  vg2_zero<<<40, 256, 0, stream>>>(Vm, lat2U, lat2I, latTu, latTi, latU);
  // L12: hyp<1>  (H1, out)
  hyp_mfma<1><<<NBM, 256, 0, stream>>>(
      uuHb, latTu, latTi, Gb, prevb, e0bf, H1, out);
}